// Round 5
// baseline (712.355 us; speedup 1.0000x reference)
//
#include <hip/hip_runtime.h>
#include <hip/hip_bf16.h>

#define B_ 16
#define N_ 8192
#define G_ 128
#define K_ 32
#define C_ 384
#define EPSV 1e-5f

typedef __attribute__((ext_vector_type(8))) short bf16x8;
typedef __attribute__((ext_vector_type(8))) unsigned short u16x8;
typedef __attribute__((ext_vector_type(4))) float f32x4;
typedef __attribute__((ext_vector_type(2))) float f32x2;

__device__ __forceinline__ unsigned short f2b(float f){
  unsigned int u = __float_as_uint(f);
  u += 0x7fffu + ((u >> 16) & 1u);      // RNE (no NaNs in this model)
  return (unsigned short)(u >> 16);
}
__device__ __forceinline__ float b2f(unsigned short s){
  return __uint_as_float(((unsigned int)s) << 16);
}
// exact-order squared distance: ((dx*dx + dy*dy) + dz*dz), IEEE, no contraction
__device__ __forceinline__ float sq3(float dx, float dy, float dz){
  return __fadd_rn(__fadd_rn(__fmul_rn(dx,dx), __fmul_rn(dy,dy)), __fmul_rn(dz,dz));
}
__device__ __forceinline__ f32x2 pkmax(f32x2 a, f32x2 b){
  return f32x2{fmaxf(a.x,b.x), fmaxf(a.y,b.y)};
}

// ---------------- weight f32->bf16 pre-conversion ----------------
__global__ __launch_bounds__(256) void prep_kernel(
    const float* __restrict__ w2, const float* __restrict__ w3,
    const float* __restrict__ w4, unsigned short* __restrict__ w2b,
    unsigned short* __restrict__ w3b, unsigned short* __restrict__ w4b){
  int i = blockIdx.x*256 + threadIdx.x;
  if (i < 32768){ w2b[i] = f2b(w2[i]); return; }
  i -= 32768;
  if (i < 262144){ w3b[i] = f2b(w3[i]); return; }
  i -= 262144;
  if (i < 196608){ w4b[i] = f2b(w4[i]); }
}

// ---------------- FPS: 256 thr, packed-f32 update, deferred argmax, 1 barrier/step ----------------
// waves_per_eu(1,1): pins allocator target to 1 wave/EU -> full 512-VGPR budget, no spill of the
// 128-float point state. Only 16 blocks exist; occupancy is irrelevant.
__attribute__((amdgpu_flat_work_group_size(256,256), amdgpu_waves_per_eu(1,1)))
__global__ void fps_morton_kernel(const float* __restrict__ xyz,
                                  float* __restrict__ centers_ord){
  const int b = blockIdx.x, t = threadIdx.x, w = t >> 6;
  const int lane = t & 63;
  const float* xb = xyz + (size_t)b*N_*3;
  __shared__ __align__(16) float sval[2][4];
  __shared__ __align__(16) int   sidx[2][4];
  __shared__ float clx[G_], cly[G_], clz[G_];   // FPS-order centers, for morton
  // point p pair (j, j+16): element .x <-> n = t + j*256, .y <-> n = t + (j+16)*256
  f32x2 X[16], Y[16], Z[16], D[16];
  const float p0x = xb[0], p0y = xb[1], p0z = xb[2];
  {
#pragma clang fp contract(off)
    #pragma unroll
    for (int p = 0; p < 16; p++){
      const int n0 = t + p*256, n1 = t + (p+16)*256;
      X[p] = f32x2{xb[n0*3],   xb[n1*3]};
      Y[p] = f32x2{xb[n0*3+1], xb[n1*3+1]};
      Z[p] = f32x2{xb[n0*3+2], xb[n1*3+2]};
      const f32x2 dx = X[p] - p0x, dy = Y[p] - p0y, dz = Z[p] - p0z;
      D[p] = (dx*dx + dy*dy) + dz*dz;
    }
  }
  if (t == 0){ clx[0] = p0x; cly[0] = p0y; clz[0] = p0z; }
  int buf = 0;
  for (int g = 1; g < G_; g++){
    // deferred argmax: value-only max tree, then descending-index equality scan
    f32x2 m0 = pkmax(pkmax(pkmax(D[0],D[1]),pkmax(D[2],D[3])),
                     pkmax(pkmax(D[4],D[5]),pkmax(D[6],D[7])));
    f32x2 m1 = pkmax(pkmax(pkmax(D[8],D[9]),pkmax(D[10],D[11])),
                     pkmax(pkmax(D[12],D[13]),pkmax(D[14],D[15])));
    const f32x2 mm = pkmax(m0, m1);
    float v = fmaxf(mm.x, mm.y);
    int jl = 0;
    #pragma unroll
    for (int p = 15; p >= 0; p--) if (D[p].y == v) jl = p + 16;  // j = 31..16
    #pragma unroll
    for (int p = 15; p >= 0; p--) if (D[p].x == v) jl = p;       // j = 15..0 (lowest wins)
    int bi = t + jl*256;
    // in-wave argmax tree; ties -> lowest global index (jnp.argmax semantics)
    #pragma unroll
    for (int mk = 1; mk < 64; mk <<= 1){
      const float ov = __shfl_xor(v, mk);
      const int   oi = __shfl_xor(bi, mk);
      if (ov > v || (ov == v && oi < bi)){ v = ov; bi = oi; }
    }
    if (lane == 0){ sval[buf][w] = v; sidx[buf][w] = bi; }
    __syncthreads();
    // 4-candidate reduce, redundantly by every thread (broadcast reads)
    const float4 vv = *(const float4*)&sval[buf][0];
    const int4   ii = *(const int4*)&sidx[buf][0];
    float bv = vv.x; int bb = ii.x;
    if (vv.y > bv || (vv.y == bv && ii.y < bb)){ bv = vv.y; bb = ii.y; }
    if (vv.z > bv || (vv.z == bv && ii.z < bb)){ bv = vv.z; bb = ii.z; }
    if (vv.w > bv || (vv.w == bv && ii.w < bb)){ bv = vv.w; bb = ii.w; }
    {
#pragma clang fp contract(off)
      // winner coords: uniform-address global load (xb is L2-resident)
      const float cx = xb[bb*3], cy = xb[bb*3+1], cz = xb[bb*3+2];
      if (t == 0){ clx[g] = cx; cly[g] = cy; clz[g] = cz; }
      #pragma unroll
      for (int p = 0; p < 16; p++){
        const f32x2 dx = X[p] - cx, dy = Y[p] - cy, dz = Z[p] - cz;
        const f32x2 dn = (dx*dx + dy*dy) + dz*dz;
        D[p] = f32x2{fminf(D[p].x, dn.x), fminf(D[p].y, dn.y)};
      }
    }
    buf ^= 1;
  }
  __syncthreads();
  // ---- morton: greedy NN tour, single wave; (v,idx) tree + post-tree coord broadcast ----
  if (t < 64){
    float mcx[2], mcy[2], mcz[2]; bool mvis[2];
    #pragma unroll
    for (int j = 0; j < 2; j++){
      const int idx = lane + j*64;
      mcx[j] = clx[idx]; mcy[j] = cly[idx]; mcz[j] = clz[idx];
      mvis[j] = (idx == 0);
    }
    float curx = clx[0], cury = cly[0], curz = clz[0];
    if (lane == 0){
      centers_ord[(size_t)b*G_*3 + 0] = curx;
      centers_ord[(size_t)b*G_*3 + 1] = cury;
      centers_ord[(size_t)b*G_*3 + 2] = curz;
    }
    for (int step = 1; step < G_; step++){
      float mv; int mbi;
      {
        const float d0r = sq3(__fsub_rn(mcx[0],curx), __fsub_rn(mcy[0],cury), __fsub_rn(mcz[0],curz));
        const float d1r = sq3(__fsub_rn(mcx[1],curx), __fsub_rn(mcy[1],cury), __fsub_rn(mcz[1],curz));
        const float d0 = mvis[0] ? __builtin_inff() : d0r;
        const float d1 = mvis[1] ? __builtin_inff() : d1r;
        // lane index < lane+64 always: ties prefer slot 0
        mv = d0; mbi = lane;
        if (d1 < mv){ mv = d1; mbi = lane + 64; }
      }
      #pragma unroll
      for (int mk = 1; mk < 64; mk <<= 1){
        const float ov = __shfl_xor(mv, mk);
        const int   oi = __shfl_xor(mbi, mk);
        if (ov < mv || (ov == mv && oi < mbi)){ mv = ov; mbi = oi; }
      }
      // post-tree: winner lane broadcasts its coords (mbi is wave-uniform)
      const int wj = mbi >> 6, wl = mbi & 63;
      const float sx = wj ? mcx[1] : mcx[0];
      const float sy = wj ? mcy[1] : mcy[0];
      const float sz = wj ? mcz[1] : mcz[0];
      curx = __shfl(sx, wl); cury = __shfl(sy, wl); curz = __shfl(sz, wl);
      if (wl == lane){
        if (wj == 0) mvis[0] = true; else mvis[1] = true;
      }
      if (lane == 0){
        centers_ord[((size_t)b*G_ + step)*3 + 0] = curx;
        centers_ord[((size_t)b*G_ + step)*3 + 1] = cury;
        centers_ord[((size_t)b*G_ + step)*3 + 2] = curz;
      }
    }
  }
}

// ---------------- KNN: register-resident d2, winner-only rescan, 1 barrier/iter ----------------
// waves_per_eu(4,4): 128-VGPR budget (need ~80 incl. dd[32]) -> no spill, 4 blocks/CU resident.
__attribute__((amdgpu_flat_work_group_size(256,256), amdgpu_waves_per_eu(4,4)))
__global__ void knn_kernel(const float* __restrict__ xyz,
                           const float* __restrict__ centers_ord,
                           float* __restrict__ neigh){
  const int gp = blockIdx.x, b = blockIdx.y, t = threadIdx.x;
  const int lane = t & 63, w = t >> 6;
  __shared__ __align__(16) float sv[2][4];
  __shared__ __align__(16) int   si[2][4];
  __shared__ int list[K_];
  const float* xb = xyz + (size_t)b*N_*3;
  const float* cp = centers_ord + ((size_t)b*G_ + gp)*3;
  const float cxv = cp[0], cyv = cp[1], czv = cp[2];
  const float cc = sq3(cxv, cyv, czv);   // (cx*cx+cy*cy)+cz*cz, exact order
  float dd[32];
  float v = __builtin_inff(); int jl = 0;
  #pragma unroll
  for (int j = 0; j < 32; j++){
    const int n = t + j*256;
    const float x = xb[n*3], y = xb[n*3+1], z = xb[n*3+2];
    const float xx = sq3(x, y, z);
    const float dot = __fadd_rn(__fadd_rn(__fmul_rn(cxv,x), __fmul_rn(cyv,y)), __fmul_rn(czv,z));
    dd[j] = __fsub_rn(__fadd_rn(cc, xx), __fmul_rn(2.f, dot));
    if (dd[j] < v){ v = dd[j]; jl = j; }
  }
  int buf = 0;
  for (int it = 0; it < K_; it++){
    float tv = v; int tbi = t + jl*256;
    #pragma unroll
    for (int m = 1; m < 64; m <<= 1){
      const float ov = __shfl_xor(tv, m); const int oi = __shfl_xor(tbi, m);
      if (ov < tv || (ov == tv && oi < tbi)){ tv = ov; tbi = oi; }
    }
    if (lane == 0){ sv[buf][w] = tv; si[buf][w] = tbi; }
    __syncthreads();
    const float4 vv = *(const float4*)&sv[buf][0];
    const int4   ii = *(const int4*)&si[buf][0];
    float bv = vv.x; int bb = ii.x;
    if (vv.y < bv || (vv.y == bv && ii.y < bb)){ bv = vv.y; bb = ii.y; }
    if (vv.z < bv || (vv.z == bv && ii.z < bb)){ bv = vv.z; bb = ii.z; }
    if (vv.w < bv || (vv.w == bv && ii.w < bb)){ bv = vv.w; bb = ii.w; }
    if (t == 0) list[it] = bb;
    if ((bb & 255) == t){
      const int jw = bb >> 8;
      #pragma unroll
      for (int j = 0; j < 32; j++) if (j == jw) dd[j] = __builtin_inff();
      v = __builtin_inff(); jl = 0;
      #pragma unroll
      for (int j = 0; j < 32; j++) if (dd[j] < v){ v = dd[j]; jl = j; }
    }
    buf ^= 1;
  }
  __syncthreads();
  if (t < K_*3){
    const int k = t / 3, d = t % 3;
    const int n = list[k];
    neigh[(((size_t)b*G_ + gp)*K_ + k)*3 + d] = __fsub_rn(xb[n*3+d], cp[d]);
  }
}

// ---------------- encoder: L1(VALU) -> L2/L3/L4 (bf16 MFMA) -> maxpool + pos-embed ----------------
__device__ __forceinline__ int swzF(int row, int col){  // [32][256] bf16, XOR swizzle
  int byteo = row*512 + col*2;
  byteo ^= (row & 7) << 4;
  return byteo >> 1;
}
__device__ __forceinline__ int swzA(int row, int col){  // [32][512] bf16
  int byteo = row*1024 + col*2;
  byteo ^= (row & 7) << 4;
  return byteo >> 1;
}

// waves_per_eu(2,3): ~170-reg budget; LDS (50KB) caps at 3 blocks/CU anyway.
__attribute__((amdgpu_flat_work_group_size(256,256), amdgpu_waves_per_eu(2,3)))
__global__ void enc_kernel(
    const float* __restrict__ neigh, const float* __restrict__ centers_ord,
    const float* __restrict__ w1, const float* __restrict__ b1,
    const float* __restrict__ g1, const float* __restrict__ bt1,
    const float* __restrict__ m1, const float* __restrict__ v1,
    const unsigned short* __restrict__ w2b, const float* __restrict__ b2,
    const unsigned short* __restrict__ w3b, const float* __restrict__ b3,
    const float* __restrict__ g3, const float* __restrict__ bt3,
    const float* __restrict__ m3, const float* __restrict__ v3,
    const unsigned short* __restrict__ w4b, const float* __restrict__ b4,
    float* __restrict__ out)
{
  const int gp = blockIdx.x, b = blockIdx.y, t = threadIdx.x;
  const int lane = t & 63, w = t >> 6, lr = lane & 15, lg = lane >> 4;
  __shared__ __align__(16) unsigned short Fl[32*256];  // f (bf16, swizzled); tail reused as tok
  __shared__ __align__(16) unsigned short A3[32*512];  // relu(bn(h@w3+b3)) bf16 swizzled
  __shared__ __align__(16) unsigned short fgb[256];    // fg = max_k f, bf16 (L3 A-frag, fg half)
  __shared__ float pg[96];
  __shared__ float ctr[3];
  float* tok = (float*)Fl;  // overlay: Fl is dead once L3 is done

  const int gid = b*G_ + gp;
  if (t < 96) pg[t] = neigh[(size_t)gid*96 + t];
  if (t < 3)  ctr[t] = centers_ord[(size_t)gid*3 + t];
  __syncthreads();

  // ---- L1 (3->128) + BN + ReLU, straight into per-lane MFMA A fragments
  bf16x8 a1f[2][4];
  #pragma unroll
  for (int kt = 0; kt < 4; kt++){
    #pragma unroll
    for (int j = 0; j < 8; j++){
      const int c = kt*32 + lg*8 + j;
      const float wx = w1[c*3], wy = w1[c*3+1], wz = w1[c*3+2];
      const float sc = g1[c] * rsqrtf(v1[c] + EPSV);
      const float mm = m1[c], bb = bt1[c], bc = b1[c];
      #pragma unroll
      for (int mt = 0; mt < 2; mt++){
        const int p = mt*16 + lr;
        float v = pg[p*3]*wx + pg[p*3+1]*wy + pg[p*3+2]*wz + bc;
        v = (v - mm)*sc + bb;
        v = fmaxf(v, 0.f);
        a1f[mt][kt][j] = (short)f2b(v);
      }
    }
  }

  // ---- L2 (128->256): f = a1 @ w2^T + b2   (each wave: 64 output cols)
  f32x4 accB[2][4];
  #pragma unroll
  for (int mt = 0; mt < 2; mt++)
    #pragma unroll
    for (int nt = 0; nt < 4; nt++){
      f32x4 z = {0.f,0.f,0.f,0.f};
      accB[mt][nt] = z;
    }
  const int n0w = w*64;
  #pragma unroll
  for (int nt = 0; nt < 4; nt++){
    #pragma unroll
    for (int kt = 0; kt < 4; kt++){
      const bf16x8 bf = *(const bf16x8*)(w2b + (n0w + nt*16 + lr)*128 + kt*32 + lg*8);
      accB[0][nt] = __builtin_amdgcn_mfma_f32_16x16x32_bf16(a1f[0][kt], bf, accB[0][nt], 0,0,0);
      accB[1][nt] = __builtin_amdgcn_mfma_f32_16x16x32_bf16(a1f[1][kt], bf, accB[1][nt], 0,0,0);
    }
  }
  #pragma unroll
  for (int nt = 0; nt < 4; nt++){
    const int col = n0w + nt*16 + lr;
    const float bc = b2[col];
    #pragma unroll
    for (int mt = 0; mt < 2; mt++)
      #pragma unroll
      for (int r = 0; r < 4; r++){
        const int row = mt*16 + lg*4 + r;
        Fl[swzF(row,col)] = f2b(accB[mt][nt][r] + bc);
      }
  }
  __syncthreads();

  // ---- fg = max_k f  (bf16-monotone: bf16 inputs -> max == bf16(max f32))
  {
    float mx = -__builtin_inff();
    #pragma unroll 4
    for (int row = 0; row < 32; row++) mx = fmaxf(mx, b2f(Fl[swzF(row, t)]));
    fgb[t] = f2b(mx);
  }
  __syncthreads();

  // ---- L3 (512->512): h = [fg bcast | f], full K=512 MFMA; then BN+ReLU -> A3
  #pragma unroll
  for (int nt = 0; nt < 8; nt++){
    const int col = w*128 + nt*16 + lr;
    f32x4 a0 = {0.f,0.f,0.f,0.f}, a1v = {0.f,0.f,0.f,0.f};
    const unsigned short* wr = w3b + (size_t)col*512;
    #pragma unroll
    for (int kt = 0; kt < 16; kt++){
      const bf16x8 bfw = *(const bf16x8*)(wr + kt*32 + lg*8);
      bf16x8 af0, af1;
      if (kt < 8){
        af0 = *(const bf16x8*)&fgb[kt*32 + lg*8];   // broadcast row (same for all rows)
        af1 = af0;
      } else {
        af0 = *(const bf16x8*)&Fl[swzF(lr,      (kt-8)*32 + lg*8)];
        af1 = *(const bf16x8*)&Fl[swzF(16 + lr, (kt-8)*32 + lg*8)];
      }
      a0  = __builtin_amdgcn_mfma_f32_16x16x32_bf16(af0, bfw, a0, 0,0,0);
      a1v = __builtin_amdgcn_mfma_f32_16x16x32_bf16(af1, bfw, a1v, 0,0,0);
    }
    const float bc = b3[col];
    const float sc = g3[col]*rsqrtf(v3[col] + EPSV);
    const float mm = m3[col], bb = bt3[col];
    #pragma unroll
    for (int mt = 0; mt < 2; mt++)
      #pragma unroll
      for (int r = 0; r < 4; r++){
        const int row = mt*16 + lg*4 + r;
        float v = (mt ? a1v[r] : a0[r]) + bc;
        v = (v - mm)*sc + bb;
        v = fmaxf(v, 0.f);
        A3[swzA(row,col)] = f2b(v);
      }
  }
  __syncthreads();

  // ---- L4 (512->384) + max over K + b4 -> tok
  #pragma unroll
  for (int nt = 0; nt < 6; nt++){
    const int col = w*96 + nt*16 + lr;
    f32x4 a0 = {0.f,0.f,0.f,0.f}, a1v = {0.f,0.f,0.f,0.f};
    const unsigned short* wr = w4b + (size_t)col*512;
    #pragma unroll
    for (int kt = 0; kt < 16; kt++){
      const bf16x8 af0 = *(const bf16x8*)&A3[swzA(lr,      kt*32 + lg*8)];
      const bf16x8 af1 = *(const bf16x8*)&A3[swzA(16 + lr, kt*32 + lg*8)];
      const bf16x8 bf  = *(const bf16x8*)(wr + kt*32 + lg*8);
      a0  = __builtin_amdgcn_mfma_f32_16x16x32_bf16(af0, bf, a0, 0,0,0);
      a1v = __builtin_amdgcn_mfma_f32_16x16x32_bf16(af1, bf, a1v, 0,0,0);
    }
    float mx = fmaxf(fmaxf(fmaxf(a0[0],a0[1]), fmaxf(a0[2],a0[3])),
                     fmaxf(fmaxf(a1v[0],a1v[1]), fmaxf(a1v[2],a1v[3])));
    mx = fmaxf(mx, __shfl_xor(mx, 16));
    mx = fmaxf(mx, __shfl_xor(mx, 32));
    if (lg == 0) tok[col] = mx + b4[col];
  }
  __syncthreads();

  // ---- out = tok + pos_embed(center)
  for (int c = t; c < C_; c += 256){
    const int d = c >> 7, r = c & 127, m2 = r >> 1;
    const float e = (float)(2*m2) * (1.f/128.f);
    const float dimt = powf(10000.f, e);
    const float x2 = __fmul_rn(ctr[d], 6.28318530717958647692f);
    const float ang = __fdiv_rn(x2, dimt);
    out[(size_t)gid*C_ + c] = tok[c] + ((r & 1) ? cosf(ang) : sinf(ang));
  }
}

extern "C" void kernel_launch(void* const* d_in, const int* in_sizes, int n_in,
                              void* d_out, int out_size, void* d_ws, size_t ws_size,
                              hipStream_t stream){
  (void)in_sizes; (void)n_in; (void)out_size; (void)ws_size;
  const float* xyz = (const float*)d_in[0];
  const float* w1  = (const float*)d_in[1];
  const float* b1  = (const float*)d_in[2];
  const float* g1  = (const float*)d_in[3];
  const float* bt1 = (const float*)d_in[4];
  const float* m1  = (const float*)d_in[5];
  const float* v1  = (const float*)d_in[6];
  const float* w2  = (const float*)d_in[7];
  const float* b2  = (const float*)d_in[8];
  const float* w3  = (const float*)d_in[9];
  const float* b3  = (const float*)d_in[10];
  const float* g3  = (const float*)d_in[11];
  const float* bt3 = (const float*)d_in[12];
  const float* m3  = (const float*)d_in[13];
  const float* v3  = (const float*)d_in[14];
  const float* w4  = (const float*)d_in[15];
  const float* b4  = (const float*)d_in[16];

  char* ws = (char*)d_ws;
  float* centers_ord  = (float*)(ws + 24576);               // 24576 B
  float* neigh        = (float*)(ws + 49152);               // 786432 B
  unsigned short* w2b = (unsigned short*)(ws + 835584);     // 65536 B
  unsigned short* w3b = (unsigned short*)(ws + 901120);     // 524288 B
  unsigned short* w4b = (unsigned short*)(ws + 1425408);    // 393216 B -> total 1818624 B

  prep_kernel      <<<1920, 256, 0, stream>>>(w2, w3, w4, w2b, w3b, w4b);
  fps_morton_kernel<<<B_, 256, 0, stream>>>(xyz, centers_ord);
  knn_kernel       <<<dim3(G_, B_), 256, 0, stream>>>(xyz, centers_ord, neigh);
  enc_kernel       <<<dim3(G_, B_), 256, 0, stream>>>(neigh, centers_ord,
      w1, b1, g1, bt1, m1, v1, w2b, b2, w3b, b3, g3, bt3, m3, v3, w4b, b4,
      (float*)d_out);
}

// Round 6
// 702.170 us; speedup vs baseline: 1.0145x; 1.0145x over previous
//
#include <hip/hip_runtime.h>
#include <hip/hip_bf16.h>

#define B_ 16
#define N_ 8192
#define G_ 128
#define K_ 32
#define C_ 384
#define EPSV 1e-5f

typedef __attribute__((ext_vector_type(8))) short bf16x8;
typedef __attribute__((ext_vector_type(8))) unsigned short u16x8;
typedef __attribute__((ext_vector_type(4))) float f32x4;
typedef __attribute__((ext_vector_type(2))) float f32x2;

__device__ __forceinline__ unsigned short f2b(float f){
  unsigned int u = __float_as_uint(f);
  u += 0x7fffu + ((u >> 16) & 1u);      // RNE (no NaNs in this model)
  return (unsigned short)(u >> 16);
}
__device__ __forceinline__ float b2f(unsigned short s){
  return __uint_as_float(((unsigned int)s) << 16);
}
// exact-order squared distance: ((dx*dx + dy*dy) + dz*dz), IEEE, no contraction
__device__ __forceinline__ float sq3(float dx, float dy, float dz){
  return __fadd_rn(__fadd_rn(__fmul_rn(dx,dx), __fmul_rn(dy,dy)), __fmul_rn(dz,dz));
}
__device__ __forceinline__ f32x2 pkmax(f32x2 a, f32x2 b){
  return f32x2{fmaxf(a.x,b.x), fmaxf(a.y,b.y)};
}

// ---------------- weight f32->bf16 pre-conversion ----------------
__global__ __launch_bounds__(256) void prep_kernel(
    const float* __restrict__ w2, const float* __restrict__ w3,
    const float* __restrict__ w4, unsigned short* __restrict__ w2b,
    unsigned short* __restrict__ w3b, unsigned short* __restrict__ w4b){
  int i = blockIdx.x*256 + threadIdx.x;
  if (i < 32768){ w2b[i] = f2b(w2[i]); return; }
  i -= 32768;
  if (i < 262144){ w3b[i] = f2b(w3[i]); return; }
  i -= 262144;
  if (i < 196608){ w4b[i] = f2b(w4[i]); }
}

// ---------------- FPS: 512 thr (2 waves/EU), 16 pts/thread, 1 barrier/step ----------------
// 64 state VGPRs/thread fits the default 2-waves/EU 256-reg budget: register-resident, no AGPR traffic.
__attribute__((amdgpu_flat_work_group_size(512,512), amdgpu_waves_per_eu(2,2)))
__global__ void fps_morton_kernel(const float* __restrict__ xyz,
                                  float* __restrict__ centers_ord){
  const int b = blockIdx.x, t = threadIdx.x, w = t >> 6;
  const int lane = t & 63;
  const float* xb = xyz + (size_t)b*N_*3;
  __shared__ __align__(16) float sval[2][8];
  __shared__ __align__(16) int   sidx[2][8];
  __shared__ float clx[G_], cly[G_], clz[G_];   // FPS-order centers, for morton
  // pair p: .x <-> n = t + p*512, .y <-> n = t + (p+8)*512
  f32x2 X[8], Y[8], Z[8], D[8];
  const float p0x = xb[0], p0y = xb[1], p0z = xb[2];
  {
#pragma clang fp contract(off)
    #pragma unroll
    for (int p = 0; p < 8; p++){
      const int n0 = t + p*512, n1 = t + (p+8)*512;
      X[p] = f32x2{xb[n0*3],   xb[n1*3]};
      Y[p] = f32x2{xb[n0*3+1], xb[n1*3+1]};
      Z[p] = f32x2{xb[n0*3+2], xb[n1*3+2]};
      const f32x2 dx = X[p] - p0x, dy = Y[p] - p0y, dz = Z[p] - p0z;
      D[p] = (dx*dx + dy*dy) + dz*dz;
    }
  }
  if (t == 0){ clx[0] = p0x; cly[0] = p0y; clz[0] = p0z; }
  int buf = 0;
  for (int g = 1; g < G_; g++){
    // deferred argmax: value-only max tree, then descending-index equality scan
    const f32x2 mm = pkmax(pkmax(pkmax(D[0],D[1]),pkmax(D[2],D[3])),
                           pkmax(pkmax(D[4],D[5]),pkmax(D[6],D[7])));
    float v = fmaxf(mm.x, mm.y);
    int jl = 0;
    #pragma unroll
    for (int p = 7; p >= 0; p--) if (D[p].y == v) jl = p + 8;   // j = 15..8
    #pragma unroll
    for (int p = 7; p >= 0; p--) if (D[p].x == v) jl = p;       // j = 7..0 (lowest wins)
    int bi = t + jl*512;
    // in-wave argmax tree; ties -> lowest global index (jnp.argmax semantics)
    #pragma unroll
    for (int mk = 1; mk < 64; mk <<= 1){
      const float ov = __shfl_xor(v, mk);
      const int   oi = __shfl_xor(bi, mk);
      if (ov > v || (ov == v && oi < bi)){ v = ov; bi = oi; }
    }
    if (lane == 0){ sval[buf][w] = v; sidx[buf][w] = bi; }
    __syncthreads();
    // 8-candidate reduce, redundantly by every thread (broadcast LDS reads)
    const float4* vp = (const float4*)&sval[buf][0];
    const int4*   ip = (const int4*)&sidx[buf][0];
    const float4 va = vp[0], vb2 = vp[1];
    const int4   ia = ip[0], ib2 = ip[1];
    float bv = va.x; int bb = ia.x;
#define UPD(vv, ii) if ((vv) > bv || ((vv) == bv && (ii) < bb)){ bv = (vv); bb = (ii); }
    UPD(va.y, ia.y)  UPD(va.z, ia.z)  UPD(va.w, ia.w)
    UPD(vb2.x, ib2.x) UPD(vb2.y, ib2.y) UPD(vb2.z, ib2.z) UPD(vb2.w, ib2.w)
#undef UPD
    {
#pragma clang fp contract(off)
      // winner coords: wave-uniform scalar load (xb is L2-resident)
      const int ubb = __builtin_amdgcn_readfirstlane(bb);
      const float cx = xb[ubb*3], cy = xb[ubb*3+1], cz = xb[ubb*3+2];
      if (t == 0){ clx[g] = cx; cly[g] = cy; clz[g] = cz; }
      #pragma unroll
      for (int p = 0; p < 8; p++){
        const f32x2 dx = X[p] - cx, dy = Y[p] - cy, dz = Z[p] - cz;
        const f32x2 dn = (dx*dx + dy*dy) + dz*dz;
        D[p] = f32x2{fminf(D[p].x, dn.x), fminf(D[p].y, dn.y)};
      }
    }
    buf ^= 1;
  }
  __syncthreads();
  // ---- morton: greedy NN tour, single wave; (v,idx) tree + post-tree coord broadcast ----
  if (t < 64){
    float mcx[2], mcy[2], mcz[2]; bool mvis[2];
    #pragma unroll
    for (int j = 0; j < 2; j++){
      const int idx = lane + j*64;
      mcx[j] = clx[idx]; mcy[j] = cly[idx]; mcz[j] = clz[idx];
      mvis[j] = (idx == 0);
    }
    float curx = clx[0], cury = cly[0], curz = clz[0];
    if (lane == 0){
      centers_ord[(size_t)b*G_*3 + 0] = curx;
      centers_ord[(size_t)b*G_*3 + 1] = cury;
      centers_ord[(size_t)b*G_*3 + 2] = curz;
    }
    for (int step = 1; step < G_; step++){
      float mv; int mbi;
      {
        const float d0r = sq3(__fsub_rn(mcx[0],curx), __fsub_rn(mcy[0],cury), __fsub_rn(mcz[0],curz));
        const float d1r = sq3(__fsub_rn(mcx[1],curx), __fsub_rn(mcy[1],cury), __fsub_rn(mcz[1],curz));
        const float d0 = mvis[0] ? __builtin_inff() : d0r;
        const float d1 = mvis[1] ? __builtin_inff() : d1r;
        mv = d0; mbi = lane;                 // lane < lane+64: ties prefer slot 0
        if (d1 < mv){ mv = d1; mbi = lane + 64; }
      }
      #pragma unroll
      for (int mk = 1; mk < 64; mk <<= 1){
        const float ov = __shfl_xor(mv, mk);
        const int   oi = __shfl_xor(mbi, mk);
        if (ov < mv || (ov == mv && oi < mbi)){ mv = ov; mbi = oi; }
      }
      const int wj = mbi >> 6, wl = mbi & 63;
      const float sx = wj ? mcx[1] : mcx[0];
      const float sy = wj ? mcy[1] : mcy[0];
      const float sz = wj ? mcz[1] : mcz[0];
      curx = __shfl(sx, wl); cury = __shfl(sy, wl); curz = __shfl(sz, wl);
      if (wl == lane){
        if (wj == 0) mvis[0] = true; else mvis[1] = true;
      }
      if (lane == 0){
        centers_ord[((size_t)b*G_ + step)*3 + 0] = curx;
        centers_ord[((size_t)b*G_ + step)*3 + 1] = cury;
        centers_ord[((size_t)b*G_ + step)*3 + 2] = curz;
      }
    }
  }
}

// ---------------- KNN: register-resident d2, winner-only rescan, 1 barrier/iter ----------------
__global__ __launch_bounds__(256, 2) void knn_kernel(const float* __restrict__ xyz,
                                                     const float* __restrict__ centers_ord,
                                                     float* __restrict__ neigh){
  const int gp = blockIdx.x, b = blockIdx.y, t = threadIdx.x;
  const int lane = t & 63, w = t >> 6;
  __shared__ __align__(16) float sv[2][4];
  __shared__ __align__(16) int   si[2][4];
  __shared__ int list[K_];
  const float* xb = xyz + (size_t)b*N_*3;
  const float* cp = centers_ord + ((size_t)b*G_ + gp)*3;
  const float cxv = cp[0], cyv = cp[1], czv = cp[2];
  const float cc = sq3(cxv, cyv, czv);   // (cx*cx+cy*cy)+cz*cz, exact order
  float dd[32];
  float v = __builtin_inff(); int jl = 0;
  #pragma unroll
  for (int j = 0; j < 32; j++){
    const int n = t + j*256;
    const float x = xb[n*3], y = xb[n*3+1], z = xb[n*3+2];
    const float xx = sq3(x, y, z);
    const float dot = __fadd_rn(__fadd_rn(__fmul_rn(cxv,x), __fmul_rn(cyv,y)), __fmul_rn(czv,z));
    dd[j] = __fsub_rn(__fadd_rn(cc, xx), __fmul_rn(2.f, dot));
    if (dd[j] < v){ v = dd[j]; jl = j; }
  }
  int buf = 0;
  for (int it = 0; it < K_; it++){
    float tv = v; int tbi = t + jl*256;
    #pragma unroll
    for (int m = 1; m < 64; m <<= 1){
      const float ov = __shfl_xor(tv, m); const int oi = __shfl_xor(tbi, m);
      if (ov < tv || (ov == tv && oi < tbi)){ tv = ov; tbi = oi; }
    }
    if (lane == 0){ sv[buf][w] = tv; si[buf][w] = tbi; }
    __syncthreads();
    const float4 vv = *(const float4*)&sv[buf][0];
    const int4   ii = *(const int4*)&si[buf][0];
    float bv = vv.x; int bb = ii.x;
    if (vv.y < bv || (vv.y == bv && ii.y < bb)){ bv = vv.y; bb = ii.y; }
    if (vv.z < bv || (vv.z == bv && ii.z < bb)){ bv = vv.z; bb = ii.z; }
    if (vv.w < bv || (vv.w == bv && ii.w < bb)){ bv = vv.w; bb = ii.w; }
    if (t == 0) list[it] = bb;
    if ((bb & 255) == t){
      const int jw = bb >> 8;
      #pragma unroll
      for (int j = 0; j < 32; j++) if (j == jw) dd[j] = __builtin_inff();
      v = __builtin_inff(); jl = 0;
      #pragma unroll
      for (int j = 0; j < 32; j++) if (dd[j] < v){ v = dd[j]; jl = j; }
    }
    buf ^= 1;
  }
  __syncthreads();
  if (t < K_*3){
    const int k = t / 3, d = t % 3;
    const int n = list[k];
    neigh[(((size_t)b*G_ + gp)*K_ + k)*3 + d] = __fsub_rn(xb[n*3+d], cp[d]);
  }
}

// ---------------- encoder: L1(VALU) -> L2/L3/L4 (bf16 MFMA, batched B loads) ----------------
__device__ __forceinline__ int swzF(int row, int col){  // [32][256] bf16, XOR swizzle
  int byteo = row*512 + col*2;
  byteo ^= (row & 7) << 4;
  return byteo >> 1;
}
__device__ __forceinline__ int swzA(int row, int col){  // [32][512] bf16
  int byteo = row*1024 + col*2;
  byteo ^= (row & 7) << 4;
  return byteo >> 1;
}

// launch_bounds(256,2): 256-VGPR cap -> room to batch 16 B-frags + hoisted A-frags in registers.
__global__ __launch_bounds__(256, 2) void enc_kernel(
    const float* __restrict__ neigh, const float* __restrict__ centers_ord,
    const float* __restrict__ w1, const float* __restrict__ b1,
    const float* __restrict__ g1, const float* __restrict__ bt1,
    const float* __restrict__ m1, const float* __restrict__ v1,
    const unsigned short* __restrict__ w2b, const float* __restrict__ b2,
    const unsigned short* __restrict__ w3b, const float* __restrict__ b3,
    const float* __restrict__ g3, const float* __restrict__ bt3,
    const float* __restrict__ m3, const float* __restrict__ v3,
    const unsigned short* __restrict__ w4b, const float* __restrict__ b4,
    float* __restrict__ out)
{
  const int gp = blockIdx.x, b = blockIdx.y, t = threadIdx.x;
  const int lane = t & 63, w = t >> 6, lr = lane & 15, lg = lane >> 4;
  __shared__ __align__(16) unsigned short Fl[32*256];  // f (bf16, swizzled); tail reused as tok
  __shared__ __align__(16) unsigned short A3[32*512];  // relu(bn(h@w3+b3)) bf16 swizzled
  __shared__ __align__(16) unsigned short fgb[256];    // fg = max_k f, bf16
  __shared__ float pg[96];
  __shared__ float ctr[3];
  float* tok = (float*)Fl;  // overlay: Fl is dead once L3 is done

  const int gid = b*G_ + gp;
  if (t < 96) pg[t] = neigh[(size_t)gid*96 + t];
  if (t < 3)  ctr[t] = centers_ord[(size_t)gid*3 + t];
  __syncthreads();

  // ---- L1 (3->128) + BN + ReLU, straight into per-lane MFMA A fragments
  bf16x8 a1f[2][4];
  #pragma unroll
  for (int kt = 0; kt < 4; kt++){
    #pragma unroll
    for (int j = 0; j < 8; j++){
      const int c = kt*32 + lg*8 + j;
      const float wx = w1[c*3], wy = w1[c*3+1], wz = w1[c*3+2];
      const float sc = g1[c] * rsqrtf(v1[c] + EPSV);
      const float mm = m1[c], bb = bt1[c], bc = b1[c];
      #pragma unroll
      for (int mt = 0; mt < 2; mt++){
        const int p = mt*16 + lr;
        float v = pg[p*3]*wx + pg[p*3+1]*wy + pg[p*3+2]*wz + bc;
        v = (v - mm)*sc + bb;
        v = fmaxf(v, 0.f);
        a1f[mt][kt][j] = (short)f2b(v);
      }
    }
  }

  // ---- L2 (128->256): f = a1 @ w2^T + b2  (batched B loads: 16 in flight, then 32 MFMAs)
  const int n0w = w*64;
  {
    bf16x8 Bk[16];
    #pragma unroll
    for (int i = 0; i < 16; i++){
      const int nt = i >> 2, kt = i & 3;
      Bk[i] = *(const bf16x8*)(w2b + (size_t)(n0w + nt*16 + lr)*128 + kt*32 + lg*8);
    }
    f32x4 accB[2][4];
    #pragma unroll
    for (int mt = 0; mt < 2; mt++)
      #pragma unroll
      for (int nt = 0; nt < 4; nt++){
        f32x4 z = {0.f,0.f,0.f,0.f};
        accB[mt][nt] = z;
      }
    #pragma unroll
    for (int nt = 0; nt < 4; nt++)
      #pragma unroll
      for (int kt = 0; kt < 4; kt++){
        accB[0][nt] = __builtin_amdgcn_mfma_f32_16x16x32_bf16(a1f[0][kt], Bk[nt*4+kt], accB[0][nt], 0,0,0);
        accB[1][nt] = __builtin_amdgcn_mfma_f32_16x16x32_bf16(a1f[1][kt], Bk[nt*4+kt], accB[1][nt], 0,0,0);
      }
    #pragma unroll
    for (int nt = 0; nt < 4; nt++){
      const int col = n0w + nt*16 + lr;
      const float bc = b2[col];
      #pragma unroll
      for (int mt = 0; mt < 2; mt++)
        #pragma unroll
        for (int r = 0; r < 4; r++){
          const int row = mt*16 + lg*4 + r;
          Fl[swzF(row,col)] = f2b(accB[mt][nt][r] + bc);
        }
    }
  }
  __syncthreads();

  // ---- fg = max_k f  (bf16-monotone: bf16 inputs -> max == bf16(max f32))
  {
    float mx = -__builtin_inff();
    #pragma unroll 4
    for (int row = 0; row < 32; row++) mx = fmaxf(mx, b2f(Fl[swzF(row, t)]));
    fgb[t] = f2b(mx);
  }
  __syncthreads();

  // ---- L3 (512->512): h = [fg bcast | f], K=512 MFMA; A-frags hoisted, B batched per nt
  {
    bf16x8 afg[8], afl0[8], afl1[8];
    #pragma unroll
    for (int k8 = 0; k8 < 8; k8++){
      afg[k8]  = *(const bf16x8*)&fgb[k8*32 + lg*8];
      afl0[k8] = *(const bf16x8*)&Fl[swzF(lr,      k8*32 + lg*8)];
      afl1[k8] = *(const bf16x8*)&Fl[swzF(16 + lr, k8*32 + lg*8)];
    }
    #pragma unroll
    for (int nt = 0; nt < 8; nt++){
      const int col = w*128 + nt*16 + lr;
      const unsigned short* wr = w3b + (size_t)col*512;
      bf16x8 Bk[16];
      #pragma unroll
      for (int kt = 0; kt < 16; kt++) Bk[kt] = *(const bf16x8*)(wr + kt*32 + lg*8);
      f32x4 a0 = {0.f,0.f,0.f,0.f}, a1v = {0.f,0.f,0.f,0.f};
      #pragma unroll
      for (int k8 = 0; k8 < 8; k8++){
        a0  = __builtin_amdgcn_mfma_f32_16x16x32_bf16(afg[k8], Bk[k8], a0, 0,0,0);
        a1v = __builtin_amdgcn_mfma_f32_16x16x32_bf16(afg[k8], Bk[k8], a1v, 0,0,0);
      }
      #pragma unroll
      for (int k8 = 0; k8 < 8; k8++){
        a0  = __builtin_amdgcn_mfma_f32_16x16x32_bf16(afl0[k8], Bk[8+k8], a0, 0,0,0);
        a1v = __builtin_amdgcn_mfma_f32_16x16x32_bf16(afl1[k8], Bk[8+k8], a1v, 0,0,0);
      }
      const float bc = b3[col];
      const float sc = g3[col]*rsqrtf(v3[col] + EPSV);
      const float mm = m3[col], bb = bt3[col];
      #pragma unroll
      for (int mt = 0; mt < 2; mt++)
        #pragma unroll
        for (int r = 0; r < 4; r++){
          const int row = mt*16 + lg*4 + r;
          float v = (mt ? a1v[r] : a0[r]) + bc;
          v = (v - mm)*sc + bb;
          v = fmaxf(v, 0.f);
          A3[swzA(row,col)] = f2b(v);
        }
    }
  }
  __syncthreads();

  // ---- L4 (512->384) + max over K + b4 -> tok  (A hoisted, B batched per nt)
  {
    bf16x8 aa0[16], aa1[16];
    #pragma unroll
    for (int kt = 0; kt < 16; kt++){
      aa0[kt] = *(const bf16x8*)&A3[swzA(lr,      kt*32 + lg*8)];
      aa1[kt] = *(const bf16x8*)&A3[swzA(16 + lr, kt*32 + lg*8)];
    }
    #pragma unroll
    for (int nt = 0; nt < 6; nt++){
      const int col = w*96 + nt*16 + lr;
      const unsigned short* wr = w4b + (size_t)col*512;
      bf16x8 Bk[16];
      #pragma unroll
      for (int kt = 0; kt < 16; kt++) Bk[kt] = *(const bf16x8*)(wr + kt*32 + lg*8);
      f32x4 a0 = {0.f,0.f,0.f,0.f}, a1v = {0.f,0.f,0.f,0.f};
      #pragma unroll
      for (int kt = 0; kt < 16; kt++){
        a0  = __builtin_amdgcn_mfma_f32_16x16x32_bf16(aa0[kt], Bk[kt], a0, 0,0,0);
        a1v = __builtin_amdgcn_mfma_f32_16x16x32_bf16(aa1[kt], Bk[kt], a1v, 0,0,0);
      }
      float mx = fmaxf(fmaxf(fmaxf(a0[0],a0[1]), fmaxf(a0[2],a0[3])),
                       fmaxf(fmaxf(a1v[0],a1v[1]), fmaxf(a1v[2],a1v[3])));
      mx = fmaxf(mx, __shfl_xor(mx, 16));
      mx = fmaxf(mx, __shfl_xor(mx, 32));
      if (lg == 0) tok[col] = mx + b4[col];
    }
  }
  __syncthreads();

  // ---- out = tok + pos_embed(center)
  for (int c = t; c < C_; c += 256){
    const int d = c >> 7, r = c & 127, m2 = r >> 1;
    const float e = (float)(2*m2) * (1.f/128.f);
    const float dimt = powf(10000.f, e);
    const float x2 = __fmul_rn(ctr[d], 6.28318530717958647692f);
    const float ang = __fdiv_rn(x2, dimt);
    out[(size_t)gid*C_ + c] = tok[c] + ((r & 1) ? cosf(ang) : sinf(ang));
  }
}

extern "C" void kernel_launch(void* const* d_in, const int* in_sizes, int n_in,
                              void* d_out, int out_size, void* d_ws, size_t ws_size,
                              hipStream_t stream){
  (void)in_sizes; (void)n_in; (void)out_size; (void)ws_size;
  const float* xyz = (const float*)d_in[0];
  const float* w1  = (const float*)d_in[1];
  const float* b1  = (const float*)d_in[2];
  const float* g1  = (const float*)d_in[3];
  const float* bt1 = (const float*)d_in[4];
  const float* m1  = (const float*)d_in[5];
  const float* v1  = (const float*)d_in[6];
  const float* w2  = (const float*)d_in[7];
  const float* b2  = (const float*)d_in[8];
  const float* w3  = (const float*)d_in[9];
  const float* b3  = (const float*)d_in[10];
  const float* g3  = (const float*)d_in[11];
  const float* bt3 = (const float*)d_in[12];
  const float* m3  = (const float*)d_in[13];
  const float* v3  = (const float*)d_in[14];
  const float* w4  = (const float*)d_in[15];
  const float* b4  = (const float*)d_in[16];

  char* ws = (char*)d_ws;
  float* centers_ord  = (float*)(ws + 24576);               // 24576 B
  float* neigh        = (float*)(ws + 49152);               // 786432 B
  unsigned short* w2b = (unsigned short*)(ws + 835584);     // 65536 B
  unsigned short* w3b = (unsigned short*)(ws + 901120);     // 524288 B
  unsigned short* w4b = (unsigned short*)(ws + 1425408);    // 393216 B -> total 1818624 B

  prep_kernel      <<<1920, 256, 0, stream>>>(w2, w3, w4, w2b, w3b, w4b);
  fps_morton_kernel<<<B_, 512, 0, stream>>>(xyz, centers_ord);
  knn_kernel       <<<dim3(G_, B_), 256, 0, stream>>>(xyz, centers_ord, neigh);
  enc_kernel       <<<dim3(G_, B_), 256, 0, stream>>>(neigh, centers_ord,
      w1, b1, g1, bt1, m1, v1, w2b, b2, w3b, b3, g3, bt3, m3, v3, w4b, b4,
      (float*)d_out);
}

// Round 7
// 595.087 us; speedup vs baseline: 1.1971x; 1.1799x over previous
//
#include <hip/hip_runtime.h>
#include <hip/hip_bf16.h>

#define B_ 16
#define N_ 8192
#define G_ 128
#define K_ 32
#define C_ 384
#define EPSV 1e-5f

typedef __attribute__((ext_vector_type(8))) short bf16x8;
typedef __attribute__((ext_vector_type(8))) unsigned short u16x8;
typedef __attribute__((ext_vector_type(4))) float f32x4;
typedef __attribute__((ext_vector_type(2))) float f32x2;

__device__ __forceinline__ unsigned short f2b(float f){
  unsigned int u = __float_as_uint(f);
  u += 0x7fffu + ((u >> 16) & 1u);      // RNE (no NaNs in this model)
  return (unsigned short)(u >> 16);
}
__device__ __forceinline__ float b2f(unsigned short s){
  return __uint_as_float(((unsigned int)s) << 16);
}
// exact-order squared distance: ((dx*dx + dy*dy) + dz*dz), IEEE, no contraction
__device__ __forceinline__ float sq3(float dx, float dy, float dz){
  return __fadd_rn(__fadd_rn(__fmul_rn(dx,dx), __fmul_rn(dy,dy)), __fmul_rn(dz,dz));
}
__device__ __forceinline__ f32x2 pkmax(f32x2 a, f32x2 b){
  return f32x2{fmaxf(a.x,b.x), fmaxf(a.y,b.y)};
}
// total-order encode: monotone f32 -> u32 (handles negatives from cancellation)
__device__ __forceinline__ unsigned fenc(float f){
  unsigned u = __float_as_uint(f);
  return ((int)u >= 0) ? (u | 0x80000000u) : ~u;
}

// ---- full-wave DPP reductions (VALU-only; result in lane 63) ----
// old=src, bound_ctrl=false: masked/OOB lanes keep own value -> identity-safe for min AND max.
#define DPP_MAXU_STAGE(r, CTRL) { \
  unsigned _o = (unsigned)__builtin_amdgcn_update_dpp((int)(r), (int)(r), (CTRL), 0xf, 0xf, false); \
  (r) = ((r) > _o) ? (r) : _o; }
#define DPP_MAXU_ALL(r) \
  DPP_MAXU_STAGE(r, 0x111) DPP_MAXU_STAGE(r, 0x112) DPP_MAXU_STAGE(r, 0x114) \
  DPP_MAXU_STAGE(r, 0x118) DPP_MAXU_STAGE(r, 0x142) DPP_MAXU_STAGE(r, 0x143)
#define DPP_MINU_STAGE(r, CTRL) { \
  unsigned _o = (unsigned)__builtin_amdgcn_update_dpp((int)(r), (int)(r), (CTRL), 0xf, 0xf, false); \
  (r) = ((r) < _o) ? (r) : _o; }
#define DPP_MINU_ALL(r) \
  DPP_MINU_STAGE(r, 0x111) DPP_MINU_STAGE(r, 0x112) DPP_MINU_STAGE(r, 0x114) \
  DPP_MINU_STAGE(r, 0x118) DPP_MINU_STAGE(r, 0x142) DPP_MINU_STAGE(r, 0x143)

// ---------------- weight f32->bf16 pre-conversion ----------------
__global__ __launch_bounds__(256) void prep_kernel(
    const float* __restrict__ w2, const float* __restrict__ w3,
    const float* __restrict__ w4, unsigned short* __restrict__ w2b,
    unsigned short* __restrict__ w3b, unsigned short* __restrict__ w4b){
  int i = blockIdx.x*256 + threadIdx.x;
  if (i < 32768){ w2b[i] = f2b(w2[i]); return; }
  i -= 32768;
  if (i < 262144){ w3b[i] = f2b(w3[i]); return; }
  i -= 262144;
  if (i < 196608){ w4b[i] = f2b(w4[i]); }
}

// ---------------- FPS: contiguous ownership + DPP value-tree + ballot ----------------
// Thread t owns points [32t, 32t+32): lane order == global-index order, so
// ballot+ffs gives the lowest-index tie winner exactly (jnp.argmax semantics).
__attribute__((amdgpu_flat_work_group_size(256,256), amdgpu_waves_per_eu(1,1)))
__global__ void fps_morton_kernel(const float* __restrict__ xyz,
                                  float* __restrict__ centers_ord){
  const int b = blockIdx.x, t = threadIdx.x, w = t >> 6;
  const int lane = t & 63;
  const float* xb = xyz + (size_t)b*N_*3;
  __shared__ __align__(16) float sval[2][4];
  __shared__ __align__(16) int   sidx[2][4];
  __shared__ float clx[G_], cly[G_], clz[G_];   // FPS-order centers, for morton
  const int base = t*32;                         // first owned point index
  // pair p holds local points (2p, 2p+1)
  f32x2 X[16], Y[16], Z[16], D[16];
  const float p0x = xb[0], p0y = xb[1], p0z = xb[2];
  {
#pragma clang fp contract(off)
    float s[96];
    const float4* src = (const float4*)(xb + (size_t)base*3);
    #pragma unroll
    for (int q = 0; q < 24; q++) ((float4*)s)[q] = src[q];
    #pragma unroll
    for (int p = 0; p < 16; p++){
      X[p] = f32x2{s[6*p+0], s[6*p+3]};
      Y[p] = f32x2{s[6*p+1], s[6*p+4]};
      Z[p] = f32x2{s[6*p+2], s[6*p+5]};
      const f32x2 dx = X[p] - p0x, dy = Y[p] - p0y, dz = Z[p] - p0z;
      D[p] = (dx*dx + dy*dy) + dz*dz;
    }
  }
  if (t == 0){ clx[0] = p0x; cly[0] = p0y; clz[0] = p0z; }
  int buf = 0;
  for (int g = 1; g < G_; g++){
    // lane-local max + deferred lowest-index scan (interleaved descending)
    const f32x2 mm = pkmax(pkmax(pkmax(pkmax(D[0],D[1]),pkmax(D[2],D[3])),
                                 pkmax(pkmax(D[4],D[5]),pkmax(D[6],D[7]))),
                           pkmax(pkmax(pkmax(D[8],D[9]),pkmax(D[10],D[11])),
                                 pkmax(pkmax(D[12],D[13]),pkmax(D[14],D[15]))));
    const float v = fmaxf(mm.x, mm.y);
    int jl = 0;
    #pragma unroll
    for (int p = 15; p >= 0; p--){
      if (D[p].y == v) jl = 2*p+1;
      if (D[p].x == v) jl = 2*p;      // lower index written later -> wins ties
    }
    // wave max via DPP (dd >= 0: u32 compare == f32 compare)
    const unsigned uv = __float_as_uint(v);
    unsigned r = uv;
    DPP_MAXU_ALL(r)
    const unsigned wmax = (unsigned)__builtin_amdgcn_readlane((int)r, 63);
    const unsigned long long tie = __ballot(uv == wmax);
    const int wl = __ffsll(tie) - 1;            // lowest lane = lowest global index
    if (lane == wl){ sval[buf][w] = __uint_as_float(wmax); sidx[buf][w] = base + jl; }
    __syncthreads();
    // 4-slot reduce (slot order == index order; strict > keeps lowest n on ties)
    const float4 vv = *(const float4*)&sval[buf][0];
    const int4   ii = *(const int4*)&sidx[buf][0];
    float bv = vv.x; int bb = ii.x;
    if (vv.y > bv){ bv = vv.y; bb = ii.y; }
    if (vv.z > bv){ bv = vv.z; bb = ii.z; }
    if (vv.w > bv){ bv = vv.w; bb = ii.w; }
    {
#pragma clang fp contract(off)
      const int ubb = __builtin_amdgcn_readfirstlane(bb);
      const float cx = xb[ubb*3], cy = xb[ubb*3+1], cz = xb[ubb*3+2];
      if (t == 0){ clx[g] = cx; cly[g] = cy; clz[g] = cz; }
      #pragma unroll
      for (int p = 0; p < 16; p++){
        const f32x2 dx = X[p] - cx, dy = Y[p] - cy, dz = Z[p] - cz;
        const f32x2 dn = (dx*dx + dy*dy) + dz*dz;
        D[p] = f32x2{fminf(D[p].x, dn.x), fminf(D[p].y, dn.y)};
      }
    }
    buf ^= 1;
  }
  __syncthreads();
  // ---- morton: greedy NN tour, single wave; DPP fast path + exact fallback ----
  if (t < 64){
    float mcx[2], mcy[2], mcz[2]; bool mvis[2];
    #pragma unroll
    for (int j = 0; j < 2; j++){
      const int idx = lane + j*64;
      mcx[j] = clx[idx]; mcy[j] = cly[idx]; mcz[j] = clz[idx];
      mvis[j] = (idx == 0);
    }
    float curx = clx[0], cury = cly[0], curz = clz[0];
    if (lane == 0){
      centers_ord[(size_t)b*G_*3 + 0] = curx;
      centers_ord[(size_t)b*G_*3 + 1] = cury;
      centers_ord[(size_t)b*G_*3 + 2] = curz;
    }
    for (int step = 1; step < G_; step++){
      const float d0r = sq3(__fsub_rn(mcx[0],curx), __fsub_rn(mcy[0],cury), __fsub_rn(mcz[0],curz));
      const float d1r = sq3(__fsub_rn(mcx[1],curx), __fsub_rn(mcy[1],cury), __fsub_rn(mcz[1],curz));
      const float d0 = mvis[0] ? __builtin_inff() : d0r;
      const float d1 = mvis[1] ? __builtin_inff() : d1r;
      float mv = d0; int mi = lane;            // lane < lane+64: ties prefer slot 0
      if (d1 < mv){ mv = d1; mi = lane + 64; }
      const int wj = mi >> 6;
      const float sx = wj ? mcx[1] : mcx[0];
      const float sy = wj ? mcy[1] : mcy[0];
      const float sz = wj ? mcz[1] : mcz[0];
      // DPP value-min (all candidates non-negative or +inf -> u32 compare valid)
      const unsigned key = __float_as_uint(mv);
      unsigned r = key;
      DPP_MINU_ALL(r)
      const unsigned wmin = (unsigned)__builtin_amdgcn_readlane((int)r, 63);
      const unsigned long long tie = __ballot(key == wmin);
      int wl;
      if (__popcll(tie) == 1){
        wl = __ffsll(tie) - 1;
      } else {
        // exact fallback: (v, idx) tree, lowest center index on ties
        float tv = mv; int ti = mi;
        #pragma unroll
        for (int mk = 1; mk < 64; mk <<= 1){
          const float ov = __shfl_xor(tv, mk);
          const int   oi = __shfl_xor(ti, mk);
          if (ov < tv || (ov == tv && oi < ti)){ tv = ov; ti = oi; }
        }
        wl = ti & 63;
      }
      const int mbi = __builtin_amdgcn_readlane(mi, wl);
      curx = __uint_as_float((unsigned)__builtin_amdgcn_readlane((int)__float_as_uint(sx), wl));
      cury = __uint_as_float((unsigned)__builtin_amdgcn_readlane((int)__float_as_uint(sy), wl));
      curz = __uint_as_float((unsigned)__builtin_amdgcn_readlane((int)__float_as_uint(sz), wl));
      if (lane == wl){
        if ((mbi >> 6) == 0) mvis[0] = true; else mvis[1] = true;
      }
      if (lane == 0){
        centers_ord[((size_t)b*G_ + step)*3 + 0] = curx;
        centers_ord[((size_t)b*G_ + step)*3 + 1] = cury;
        centers_ord[((size_t)b*G_ + step)*3 + 2] = curz;
      }
    }
  }
}

// ---------------- KNN: contiguous ownership + DPP min tree + ballot ----------------
__global__ __launch_bounds__(256, 2) void knn_kernel(const float* __restrict__ xyz,
                                                     const float* __restrict__ centers_ord,
                                                     float* __restrict__ neigh){
  const int gp = blockIdx.x, b = blockIdx.y, t = threadIdx.x;
  const int lane = t & 63, w = t >> 6;
  __shared__ __align__(16) float sv[2][4];
  __shared__ __align__(16) int   si[2][4];
  __shared__ int list[K_];
  const float* xb = xyz + (size_t)b*N_*3;
  const float* cp = centers_ord + ((size_t)b*G_ + gp)*3;
  const float cxv = cp[0], cyv = cp[1], czv = cp[2];
  const float cc = sq3(cxv, cyv, czv);   // (cx*cx+cy*cy)+cz*cz, exact order
  const int base = t*32;                  // thread owns points [32t, 32t+32)
  float dd[32];
  float v = __builtin_inff(); int jl = 0;
  {
    float s[96];
    const float4* src = (const float4*)(xb + (size_t)base*3);
    #pragma unroll
    for (int q = 0; q < 24; q++) ((float4*)s)[q] = src[q];
    #pragma unroll
    for (int j = 0; j < 32; j++){
      const float x = s[3*j], y = s[3*j+1], z = s[3*j+2];
      const float xx = sq3(x, y, z);
      const float dot = __fadd_rn(__fadd_rn(__fmul_rn(cxv,x), __fmul_rn(cyv,y)), __fmul_rn(czv,z));
      dd[j] = __fsub_rn(__fadd_rn(cc, xx), __fmul_rn(2.f, dot));
      if (dd[j] < v){ v = dd[j]; jl = j; }   // ascending, strict <: lowest idx ties
    }
  }
  int buf = 0;
  for (int it = 0; it < K_; it++){
    // wave min via DPP on sign-folded keys (d2 may be slightly negative)
    const unsigned key = fenc(v);
    unsigned r = key;
    DPP_MINU_ALL(r)
    const unsigned wmin = (unsigned)__builtin_amdgcn_readlane((int)r, 63);
    const unsigned long long tie = __ballot(key == wmin);
    const int wl = __ffsll(tie) - 1;        // lowest lane = lowest global index
    if (lane == wl){ sv[buf][w] = v; si[buf][w] = base + jl; }
    __syncthreads();
    const float4 vv = *(const float4*)&sv[buf][0];
    const int4   ii = *(const int4*)&si[buf][0];
    float bv = vv.x; int bb = ii.x;
    if (vv.y < bv){ bv = vv.y; bb = ii.y; }  // strict <: slot order == n order
    if (vv.z < bv){ bv = vv.z; bb = ii.z; }
    if (vv.w < bv){ bv = vv.w; bb = ii.w; }
    if (t == 0) list[it] = bb;
    if ((bb >> 5) == t){
      const int jw = bb & 31;
      #pragma unroll
      for (int j = 0; j < 32; j++) if (j == jw) dd[j] = __builtin_inff();
      v = __builtin_inff(); jl = 0;
      #pragma unroll
      for (int j = 0; j < 32; j++) if (dd[j] < v){ v = dd[j]; jl = j; }
    }
    buf ^= 1;
  }
  __syncthreads();
  if (t < K_*3){
    const int k = t / 3, d = t % 3;
    const int n = list[k];
    neigh[(((size_t)b*G_ + gp)*K_ + k)*3 + d] = __fsub_rn(xb[n*3+d], cp[d]);
  }
}

// ---------------- encoder: L1(VALU) -> L2/L3/L4 (bf16 MFMA, batched B loads) ----------------
__device__ __forceinline__ int swzF(int row, int col){  // [32][256] bf16, XOR swizzle
  int byteo = row*512 + col*2;
  byteo ^= (row & 7) << 4;
  return byteo >> 1;
}
__device__ __forceinline__ int swzA(int row, int col){  // [32][512] bf16
  int byteo = row*1024 + col*2;
  byteo ^= (row & 7) << 4;
  return byteo >> 1;
}

// launch_bounds(256,2): 256-VGPR cap -> room to batch 16 B-frags + hoisted A-frags in registers.
__global__ __launch_bounds__(256, 2) void enc_kernel(
    const float* __restrict__ neigh, const float* __restrict__ centers_ord,
    const float* __restrict__ w1, const float* __restrict__ b1,
    const float* __restrict__ g1, const float* __restrict__ bt1,
    const float* __restrict__ m1, const float* __restrict__ v1,
    const unsigned short* __restrict__ w2b, const float* __restrict__ b2,
    const unsigned short* __restrict__ w3b, const float* __restrict__ b3,
    const float* __restrict__ g3, const float* __restrict__ bt3,
    const float* __restrict__ m3, const float* __restrict__ v3,
    const unsigned short* __restrict__ w4b, const float* __restrict__ b4,
    float* __restrict__ out)
{
  const int gp = blockIdx.x, b = blockIdx.y, t = threadIdx.x;
  const int lane = t & 63, w = t >> 6, lr = lane & 15, lg = lane >> 4;
  __shared__ __align__(16) unsigned short Fl[32*256];  // f (bf16, swizzled); tail reused as tok
  __shared__ __align__(16) unsigned short A3[32*512];  // relu(bn(h@w3+b3)) bf16 swizzled
  __shared__ __align__(16) unsigned short fgb[256];    // fg = max_k f, bf16
  __shared__ float pg[96];
  __shared__ float ctr[3];
  float* tok = (float*)Fl;  // overlay: Fl is dead once L3 is done

  const int gid = b*G_ + gp;
  if (t < 96) pg[t] = neigh[(size_t)gid*96 + t];
  if (t < 3)  ctr[t] = centers_ord[(size_t)gid*3 + t];
  __syncthreads();

  // ---- L1 (3->128) + BN + ReLU, straight into per-lane MFMA A fragments
  bf16x8 a1f[2][4];
  #pragma unroll
  for (int kt = 0; kt < 4; kt++){
    #pragma unroll
    for (int j = 0; j < 8; j++){
      const int c = kt*32 + lg*8 + j;
      const float wx = w1[c*3], wy = w1[c*3+1], wz = w1[c*3+2];
      const float sc = g1[c] * rsqrtf(v1[c] + EPSV);
      const float mm = m1[c], bb = bt1[c], bc = b1[c];
      #pragma unroll
      for (int mt = 0; mt < 2; mt++){
        const int p = mt*16 + lr;
        float v = pg[p*3]*wx + pg[p*3+1]*wy + pg[p*3+2]*wz + bc;
        v = (v - mm)*sc + bb;
        v = fmaxf(v, 0.f);
        a1f[mt][kt][j] = (short)f2b(v);
      }
    }
  }

  // ---- L2 (128->256): f = a1 @ w2^T + b2  (batched B loads: 16 in flight, then 32 MFMAs)
  const int n0w = w*64;
  {
    bf16x8 Bk[16];
    #pragma unroll
    for (int i = 0; i < 16; i++){
      const int nt = i >> 2, kt = i & 3;
      Bk[i] = *(const bf16x8*)(w2b + (size_t)(n0w + nt*16 + lr)*128 + kt*32 + lg*8);
    }
    f32x4 accB[2][4];
    #pragma unroll
    for (int mt = 0; mt < 2; mt++)
      #pragma unroll
      for (int nt = 0; nt < 4; nt++){
        f32x4 z = {0.f,0.f,0.f,0.f};
        accB[mt][nt] = z;
      }
    #pragma unroll
    for (int nt = 0; nt < 4; nt++)
      #pragma unroll
      for (int kt = 0; kt < 4; kt++){
        accB[0][nt] = __builtin_amdgcn_mfma_f32_16x16x32_bf16(a1f[0][kt], Bk[nt*4+kt], accB[0][nt], 0,0,0);
        accB[1][nt] = __builtin_amdgcn_mfma_f32_16x16x32_bf16(a1f[1][kt], Bk[nt*4+kt], accB[1][nt], 0,0,0);
      }
    #pragma unroll
    for (int nt = 0; nt < 4; nt++){
      const int col = n0w + nt*16 + lr;
      const float bc = b2[col];
      #pragma unroll
      for (int mt = 0; mt < 2; mt++)
        #pragma unroll
        for (int r = 0; r < 4; r++){
          const int row = mt*16 + lg*4 + r;
          Fl[swzF(row,col)] = f2b(accB[mt][nt][r] + bc);
        }
    }
  }
  __syncthreads();

  // ---- fg = max_k f  (bf16-monotone: bf16 inputs -> max == bf16(max f32))
  {
    float mx = -__builtin_inff();
    #pragma unroll 4
    for (int row = 0; row < 32; row++) mx = fmaxf(mx, b2f(Fl[swzF(row, t)]));
    fgb[t] = f2b(mx);
  }
  __syncthreads();

  // ---- L3 (512->512): h = [fg bcast | f], K=512 MFMA; A-frags hoisted, B batched per nt
  {
    bf16x8 afg[8], afl0[8], afl1[8];
    #pragma unroll
    for (int k8 = 0; k8 < 8; k8++){
      afg[k8]  = *(const bf16x8*)&fgb[k8*32 + lg*8];
      afl0[k8] = *(const bf16x8*)&Fl[swzF(lr,      k8*32 + lg*8)];
      afl1[k8] = *(const bf16x8*)&Fl[swzF(16 + lr, k8*32 + lg*8)];
    }
    #pragma unroll
    for (int nt = 0; nt < 8; nt++){
      const int col = w*128 + nt*16 + lr;
      const unsigned short* wr = w3b + (size_t)col*512;
      bf16x8 Bk[16];
      #pragma unroll
      for (int kt = 0; kt < 16; kt++) Bk[kt] = *(const bf16x8*)(wr + kt*32 + lg*8);
      f32x4 a0 = {0.f,0.f,0.f,0.f}, a1v = {0.f,0.f,0.f,0.f};
      #pragma unroll
      for (int k8 = 0; k8 < 8; k8++){
        a0  = __builtin_amdgcn_mfma_f32_16x16x32_bf16(afg[k8], Bk[k8], a0, 0,0,0);
        a1v = __builtin_amdgcn_mfma_f32_16x16x32_bf16(afg[k8], Bk[k8], a1v, 0,0,0);
      }
      #pragma unroll
      for (int k8 = 0; k8 < 8; k8++){
        a0  = __builtin_amdgcn_mfma_f32_16x16x32_bf16(afl0[k8], Bk[8+k8], a0, 0,0,0);
        a1v = __builtin_amdgcn_mfma_f32_16x16x32_bf16(afl1[k8], Bk[8+k8], a1v, 0,0,0);
      }
      const float bc = b3[col];
      const float sc = g3[col]*rsqrtf(v3[col] + EPSV);
      const float mm = m3[col], bb = bt3[col];
      #pragma unroll
      for (int mt = 0; mt < 2; mt++)
        #pragma unroll
        for (int r = 0; r < 4; r++){
          const int row = mt*16 + lg*4 + r;
          float v = (mt ? a1v[r] : a0[r]) + bc;
          v = (v - mm)*sc + bb;
          v = fmaxf(v, 0.f);
          A3[swzA(row,col)] = f2b(v);
        }
    }
  }
  __syncthreads();

  // ---- L4 (512->384) + max over K + b4 -> tok  (A hoisted, B batched per nt)
  {
    bf16x8 aa0[16], aa1[16];
    #pragma unroll
    for (int kt = 0; kt < 16; kt++){
      aa0[kt] = *(const bf16x8*)&A3[swzA(lr,      kt*32 + lg*8)];
      aa1[kt] = *(const bf16x8*)&A3[swzA(16 + lr, kt*32 + lg*8)];
    }
    #pragma unroll
    for (int nt = 0; nt < 6; nt++){
      const int col = w*96 + nt*16 + lr;
      const unsigned short* wr = w4b + (size_t)col*512;
      bf16x8 Bk[16];
      #pragma unroll
      for (int kt = 0; kt < 16; kt++) Bk[kt] = *(const bf16x8*)(wr + kt*32 + lg*8);
      f32x4 a0 = {0.f,0.f,0.f,0.f}, a1v = {0.f,0.f,0.f,0.f};
      #pragma unroll
      for (int kt = 0; kt < 16; kt++){
        a0  = __builtin_amdgcn_mfma_f32_16x16x32_bf16(aa0[kt], Bk[kt], a0, 0,0,0);
        a1v = __builtin_amdgcn_mfma_f32_16x16x32_bf16(aa1[kt], Bk[kt], a1v, 0,0,0);
      }
      float mx = fmaxf(fmaxf(fmaxf(a0[0],a0[1]), fmaxf(a0[2],a0[3])),
                       fmaxf(fmaxf(a1v[0],a1v[1]), fmaxf(a1v[2],a1v[3])));
      mx = fmaxf(mx, __shfl_xor(mx, 16));
      mx = fmaxf(mx, __shfl_xor(mx, 32));
      if (lg == 0) tok[col] = mx + b4[col];
    }
  }
  __syncthreads();

  // ---- out = tok + pos_embed(center)
  for (int c = t; c < C_; c += 256){
    const int d = c >> 7, r = c & 127, m2 = r >> 1;
    const float e = (float)(2*m2) * (1.f/128.f);
    const float dimt = powf(10000.f, e);
    const float x2 = __fmul_rn(ctr[d], 6.28318530717958647692f);
    const float ang = __fdiv_rn(x2, dimt);
    out[(size_t)gid*C_ + c] = tok[c] + ((r & 1) ? cosf(ang) : sinf(ang));
  }
}

extern "C" void kernel_launch(void* const* d_in, const int* in_sizes, int n_in,
                              void* d_out, int out_size, void* d_ws, size_t ws_size,
                              hipStream_t stream){
  (void)in_sizes; (void)n_in; (void)out_size; (void)ws_size;
  const float* xyz = (const float*)d_in[0];
  const float* w1  = (const float*)d_in[1];
  const float* b1  = (const float*)d_in[2];
  const float* g1  = (const float*)d_in[3];
  const float* bt1 = (const float*)d_in[4];
  const float* m1  = (const float*)d_in[5];
  const float* v1  = (const float*)d_in[6];
  const float* w2  = (const float*)d_in[7];
  const float* b2  = (const float*)d_in[8];
  const float* w3  = (const float*)d_in[9];
  const float* b3  = (const float*)d_in[10];
  const float* g3  = (const float*)d_in[11];
  const float* bt3 = (const float*)d_in[12];
  const float* m3  = (const float*)d_in[13];
  const float* v3  = (const float*)d_in[14];
  const float* w4  = (const float*)d_in[15];
  const float* b4  = (const float*)d_in[16];

  char* ws = (char*)d_ws;
  float* centers_ord  = (float*)(ws + 24576);               // 24576 B
  float* neigh        = (float*)(ws + 49152);               // 786432 B
  unsigned short* w2b = (unsigned short*)(ws + 835584);     // 65536 B
  unsigned short* w3b = (unsigned short*)(ws + 901120);     // 524288 B
  unsigned short* w4b = (unsigned short*)(ws + 1425408);    // 393216 B -> total 1818624 B

  prep_kernel      <<<1920, 256, 0, stream>>>(w2, w3, w4, w2b, w3b, w4b);
  fps_morton_kernel<<<B_, 256, 0, stream>>>(xyz, centers_ord);
  knn_kernel       <<<dim3(G_, B_), 256, 0, stream>>>(xyz, centers_ord, neigh);
  enc_kernel       <<<dim3(G_, B_), 256, 0, stream>>>(neigh, centers_ord,
      w1, b1, g1, bt1, m1, v1, w2b, b2, w3b, b3, g3, bt3, m3, v3, w4b, b4,
      (float*)d_out);
}

// Round 9
// 511.177 us; speedup vs baseline: 1.3936x; 1.1642x over previous
//
#include <hip/hip_runtime.h>
#include <hip/hip_bf16.h>

#define B_ 16
#define N_ 8192
#define G_ 128
#define K_ 32
#define C_ 384
#define EPSV 1e-5f

typedef __attribute__((ext_vector_type(8))) short bf16x8;
typedef __attribute__((ext_vector_type(8))) unsigned short u16x8;
typedef __attribute__((ext_vector_type(4))) float f32x4;
typedef __attribute__((ext_vector_type(2))) float f32x2;

__device__ __forceinline__ unsigned short f2b(float f){
  unsigned int u = __float_as_uint(f);
  u += 0x7fffu + ((u >> 16) & 1u);      // RNE (no NaNs in this model)
  return (unsigned short)(u >> 16);
}
__device__ __forceinline__ float b2f(unsigned short s){
  return __uint_as_float(((unsigned int)s) << 16);
}
// exact-order squared distance: ((dx*dx + dy*dy) + dz*dz), IEEE, no contraction
__device__ __forceinline__ float sq3(float dx, float dy, float dz){
  return __fadd_rn(__fadd_rn(__fmul_rn(dx,dx), __fmul_rn(dy,dy)), __fmul_rn(dz,dz));
}
__device__ __forceinline__ f32x2 pkmax(f32x2 a, f32x2 b){
  return f32x2{fmaxf(a.x,b.x), fmaxf(a.y,b.y)};
}
// total-order encode: monotone f32 -> u32 (handles negatives from cancellation)
__device__ __forceinline__ unsigned fenc(float f){
  unsigned u = __float_as_uint(f);
  return ((int)u >= 0) ? (u | 0x80000000u) : ~u;
}

// ---- full-wave DPP reductions (VALU-only; result in lane 63) ----
#define DPP_MAXU_STAGE(r, CTRL) { \
  unsigned _o = (unsigned)__builtin_amdgcn_update_dpp((int)(r), (int)(r), (CTRL), 0xf, 0xf, false); \
  (r) = ((r) > _o) ? (r) : _o; }
#define DPP_MAXU_ALL(r) \
  DPP_MAXU_STAGE(r, 0x111) DPP_MAXU_STAGE(r, 0x112) DPP_MAXU_STAGE(r, 0x114) \
  DPP_MAXU_STAGE(r, 0x118) DPP_MAXU_STAGE(r, 0x142) DPP_MAXU_STAGE(r, 0x143)
#define DPP_MINU_STAGE(r, CTRL) { \
  unsigned _o = (unsigned)__builtin_amdgcn_update_dpp((int)(r), (int)(r), (CTRL), 0xf, 0xf, false); \
  (r) = ((r) < _o) ? (r) : _o; }
#define DPP_MINU_ALL(r) \
  DPP_MINU_STAGE(r, 0x111) DPP_MINU_STAGE(r, 0x112) DPP_MINU_STAGE(r, 0x114) \
  DPP_MINU_STAGE(r, 0x118) DPP_MINU_STAGE(r, 0x142) DPP_MINU_STAGE(r, 0x143)

// ---------------- weight f32->bf16 pre-conversion ----------------
__global__ __launch_bounds__(256) void prep_kernel(
    const float* __restrict__ w2, const float* __restrict__ w3,
    const float* __restrict__ w4, unsigned short* __restrict__ w2b,
    unsigned short* __restrict__ w3b, unsigned short* __restrict__ w4b){
  int i = blockIdx.x*256 + threadIdx.x;
  if (i < 32768){ w2b[i] = f2b(w2[i]); return; }
  i -= 32768;
  if (i < 262144){ w3b[i] = f2b(w3[i]); return; }
  i -= 262144;
  if (i < 196608){ w4b[i] = f2b(w4[i]); }
}

// ---------------- FPS: contiguous ownership + DPP value-tree + ballot ----------------
__attribute__((amdgpu_flat_work_group_size(256,256), amdgpu_waves_per_eu(1,1)))
__global__ void fps_morton_kernel(const float* __restrict__ xyz,
                                  float* __restrict__ centers_ord){
  const int b = blockIdx.x, t = threadIdx.x, w = t >> 6;
  const int lane = t & 63;
  const float* xb = xyz + (size_t)b*N_*3;
  __shared__ __align__(16) float sval[2][4];
  __shared__ __align__(16) int   sidx[2][4];
  __shared__ float clx[G_], cly[G_], clz[G_];
  const int base = t*32;
  f32x2 X[16], Y[16], Z[16], D[16];
  const float p0x = xb[0], p0y = xb[1], p0z = xb[2];
  {
#pragma clang fp contract(off)
    float s[96];
    const float4* src = (const float4*)(xb + (size_t)base*3);
    #pragma unroll
    for (int q = 0; q < 24; q++) ((float4*)s)[q] = src[q];
    #pragma unroll
    for (int p = 0; p < 16; p++){
      X[p] = f32x2{s[6*p+0], s[6*p+3]};
      Y[p] = f32x2{s[6*p+1], s[6*p+4]};
      Z[p] = f32x2{s[6*p+2], s[6*p+5]};
      const f32x2 dx = X[p] - p0x, dy = Y[p] - p0y, dz = Z[p] - p0z;
      D[p] = (dx*dx + dy*dy) + dz*dz;
    }
  }
  if (t == 0){ clx[0] = p0x; cly[0] = p0y; clz[0] = p0z; }
  int buf = 0;
  for (int g = 1; g < G_; g++){
    const f32x2 mm = pkmax(pkmax(pkmax(pkmax(D[0],D[1]),pkmax(D[2],D[3])),
                                 pkmax(pkmax(D[4],D[5]),pkmax(D[6],D[7]))),
                           pkmax(pkmax(pkmax(D[8],D[9]),pkmax(D[10],D[11])),
                                 pkmax(pkmax(D[12],D[13]),pkmax(D[14],D[15]))));
    const float v = fmaxf(mm.x, mm.y);
    int jl = 0;
    #pragma unroll
    for (int p = 15; p >= 0; p--){
      if (D[p].y == v) jl = 2*p+1;
      if (D[p].x == v) jl = 2*p;
    }
    const unsigned uv = __float_as_uint(v);
    unsigned r = uv;
    DPP_MAXU_ALL(r)
    const unsigned wmax = (unsigned)__builtin_amdgcn_readlane((int)r, 63);
    const unsigned long long tie = __ballot(uv == wmax);
    const int wl = __ffsll(tie) - 1;
    if (lane == wl){ sval[buf][w] = __uint_as_float(wmax); sidx[buf][w] = base + jl; }
    __syncthreads();
    const float4 vv = *(const float4*)&sval[buf][0];
    const int4   ii = *(const int4*)&sidx[buf][0];
    float bv = vv.x; int bb = ii.x;
    if (vv.y > bv){ bv = vv.y; bb = ii.y; }
    if (vv.z > bv){ bv = vv.z; bb = ii.z; }
    if (vv.w > bv){ bv = vv.w; bb = ii.w; }
    {
#pragma clang fp contract(off)
      const int ubb = __builtin_amdgcn_readfirstlane(bb);
      const float cx = xb[ubb*3], cy = xb[ubb*3+1], cz = xb[ubb*3+2];
      if (t == 0){ clx[g] = cx; cly[g] = cy; clz[g] = cz; }
      #pragma unroll
      for (int p = 0; p < 16; p++){
        const f32x2 dx = X[p] - cx, dy = Y[p] - cy, dz = Z[p] - cz;
        const f32x2 dn = (dx*dx + dy*dy) + dz*dz;
        D[p] = f32x2{fminf(D[p].x, dn.x), fminf(D[p].y, dn.y)};
      }
    }
    buf ^= 1;
  }
  __syncthreads();
  if (t < 64){
    float mcx[2], mcy[2], mcz[2]; bool mvis[2];
    #pragma unroll
    for (int j = 0; j < 2; j++){
      const int idx = lane + j*64;
      mcx[j] = clx[idx]; mcy[j] = cly[idx]; mcz[j] = clz[idx];
      mvis[j] = (idx == 0);
    }
    float curx = clx[0], cury = cly[0], curz = clz[0];
    if (lane == 0){
      centers_ord[(size_t)b*G_*3 + 0] = curx;
      centers_ord[(size_t)b*G_*3 + 1] = cury;
      centers_ord[(size_t)b*G_*3 + 2] = curz;
    }
    for (int step = 1; step < G_; step++){
      const float d0r = sq3(__fsub_rn(mcx[0],curx), __fsub_rn(mcy[0],cury), __fsub_rn(mcz[0],curz));
      const float d1r = sq3(__fsub_rn(mcx[1],curx), __fsub_rn(mcy[1],cury), __fsub_rn(mcz[1],curz));
      const float d0 = mvis[0] ? __builtin_inff() : d0r;
      const float d1 = mvis[1] ? __builtin_inff() : d1r;
      float mv = d0; int mi = lane;
      if (d1 < mv){ mv = d1; mi = lane + 64; }
      const int wj = mi >> 6;
      const float sx = wj ? mcx[1] : mcx[0];
      const float sy = wj ? mcy[1] : mcy[0];
      const float sz = wj ? mcz[1] : mcz[0];
      const unsigned key = __float_as_uint(mv);
      unsigned r = key;
      DPP_MINU_ALL(r)
      const unsigned wmin = (unsigned)__builtin_amdgcn_readlane((int)r, 63);
      const unsigned long long tie = __ballot(key == wmin);
      int wl;
      if (__popcll(tie) == 1){
        wl = __ffsll(tie) - 1;
      } else {
        float tv = mv; int ti = mi;
        #pragma unroll
        for (int mk = 1; mk < 64; mk <<= 1){
          const float ov = __shfl_xor(tv, mk);
          const int   oi = __shfl_xor(ti, mk);
          if (ov < tv || (ov == tv && oi < ti)){ tv = ov; ti = oi; }
        }
        wl = ti & 63;
      }
      const int mbi = __builtin_amdgcn_readlane(mi, wl);
      curx = __uint_as_float((unsigned)__builtin_amdgcn_readlane((int)__float_as_uint(sx), wl));
      cury = __uint_as_float((unsigned)__builtin_amdgcn_readlane((int)__float_as_uint(sy), wl));
      curz = __uint_as_float((unsigned)__builtin_amdgcn_readlane((int)__float_as_uint(sz), wl));
      if (lane == wl){
        if ((mbi >> 6) == 0) mvis[0] = true; else mvis[1] = true;
      }
      if (lane == 0){
        centers_ord[((size_t)b*G_ + step)*3 + 0] = curx;
        centers_ord[((size_t)b*G_ + step)*3 + 1] = cury;
        centers_ord[((size_t)b*G_ + step)*3 + 2] = curz;
      }
    }
  }
}

// ---------------- KNN: contiguous ownership + DPP min tree + ballot ----------------
__global__ __launch_bounds__(256, 2) void knn_kernel(const float* __restrict__ xyz,
                                                     const float* __restrict__ centers_ord,
                                                     float* __restrict__ neigh){
  const int gp = blockIdx.x, b = blockIdx.y, t = threadIdx.x;
  const int lane = t & 63, w = t >> 6;
  __shared__ __align__(16) float sv[2][4];
  __shared__ __align__(16) int   si[2][4];
  __shared__ int list[K_];
  const float* xb = xyz + (size_t)b*N_*3;
  const float* cp = centers_ord + ((size_t)b*G_ + gp)*3;
  const float cxv = cp[0], cyv = cp[1], czv = cp[2];
  const float cc = sq3(cxv, cyv, czv);
  const int base = t*32;
  float dd[32];
  float v = __builtin_inff(); int jl = 0;
  {
    float s[96];
    const float4* src = (const float4*)(xb + (size_t)base*3);
    #pragma unroll
    for (int q = 0; q < 24; q++) ((float4*)s)[q] = src[q];
    #pragma unroll
    for (int j = 0; j < 32; j++){
      const float x = s[3*j], y = s[3*j+1], z = s[3*j+2];
      const float xx = sq3(x, y, z);
      const float dot = __fadd_rn(__fadd_rn(__fmul_rn(cxv,x), __fmul_rn(cyv,y)), __fmul_rn(czv,z));
      dd[j] = __fsub_rn(__fadd_rn(cc, xx), __fmul_rn(2.f, dot));
      if (dd[j] < v){ v = dd[j]; jl = j; }
    }
  }
  int buf = 0;
  for (int it = 0; it < K_; it++){
    const unsigned key = fenc(v);
    unsigned r = key;
    DPP_MINU_ALL(r)
    const unsigned wmin = (unsigned)__builtin_amdgcn_readlane((int)r, 63);
    const unsigned long long tie = __ballot(key == wmin);
    const int wl = __ffsll(tie) - 1;
    if (lane == wl){ sv[buf][w] = v; si[buf][w] = base + jl; }
    __syncthreads();
    const float4 vv = *(const float4*)&sv[buf][0];
    const int4   ii = *(const int4*)&si[buf][0];
    float bv = vv.x; int bb = ii.x;
    if (vv.y < bv){ bv = vv.y; bb = ii.y; }
    if (vv.z < bv){ bv = vv.z; bb = ii.z; }
    if (vv.w < bv){ bv = vv.w; bb = ii.w; }
    if (t == 0) list[it] = bb;
    if ((bb >> 5) == t){
      const int jw = bb & 31;
      #pragma unroll
      for (int j = 0; j < 32; j++) if (j == jw) dd[j] = __builtin_inff();
      v = __builtin_inff(); jl = 0;
      #pragma unroll
      for (int j = 0; j < 32; j++) if (dd[j] < v){ v = dd[j]; jl = j; }
    }
    buf ^= 1;
  }
  __syncthreads();
  if (t < K_*3){
    const int k = t / 3, d = t % 3;
    const int n = list[k];
    neigh[(((size_t)b*G_ + gp)*K_ + k)*3 + d] = __fsub_rn(xb[n*3+d], cp[d]);
  }
}

// ---------------- encoder: 2 groups/block, 8 waves; weights applied to both groups ----------------
__device__ __forceinline__ int swzA1(int row, int col){  // [32][128] bf16
  int byteo = row*256 + col*2;
  byteo ^= (row & 7) << 4;
  return byteo >> 1;
}
__device__ __forceinline__ int swzF(int row, int col){  // [32][256] bf16
  int byteo = row*512 + col*2;
  byteo ^= (row & 7) << 4;
  return byteo >> 1;
}
__device__ __forceinline__ int swzA(int row, int col){  // [32][512] bf16
  int byteo = row*1024 + col*2;
  byteo ^= (row & 7) << 4;
  return byteo >> 1;
}

__global__ __launch_bounds__(512, 2) void enc_kernel(
    const float* __restrict__ neigh, const float* __restrict__ centers_ord,
    const float* __restrict__ w1, const float* __restrict__ b1,
    const float* __restrict__ g1, const float* __restrict__ bt1,
    const float* __restrict__ m1, const float* __restrict__ v1,
    const unsigned short* __restrict__ w2b, const float* __restrict__ b2,
    const unsigned short* __restrict__ w3b, const float* __restrict__ b3,
    const float* __restrict__ g3, const float* __restrict__ bt3,
    const float* __restrict__ m3, const float* __restrict__ v3,
    const unsigned short* __restrict__ w4b, const float* __restrict__ b4,
    float* __restrict__ out)
{
  const int t = threadIdx.x;
  const int lane = t & 63, w = t >> 6, lr = lane & 15, lg = lane >> 4;
  const int gid0 = blockIdx.x*2;
  __shared__ __align__(16) unsigned short A1s[2][32*128];  // relu(bn(L1)) bf16, swizzled
  __shared__ __align__(16) unsigned short Fl[2][32*256];   // f bf16 swizzled; tail overlaid by tok
  __shared__ __align__(16) unsigned short A3s[2][32*512];  // relu(bn(L3)) bf16 swizzled
  __shared__ __align__(16) unsigned short fgb[2][256];     // fg bf16
  float* tokp = (float*)&Fl[0][0];                          // [2][384] overlay (Fl dead after L3)

  // ---- L1 (3->128) + BN + ReLU -> A1s (each thread: one (g,point), 16 channels)
  {
    const int g = t >> 8, rem = t & 255, p = rem >> 3, c0 = (rem & 7) * 16;
    const float* pgp = neigh + (size_t)(gid0 + g)*96 + p*3;
    const float px = pgp[0], py = pgp[1], pz = pgp[2];
    unsigned short hv[16];
    #pragma unroll
    for (int cc = 0; cc < 16; cc++){
      const int c = c0 + cc;
      const float wx = w1[c*3], wy = w1[c*3+1], wz = w1[c*3+2];
      const float sc = g1[c] * rsqrtf(v1[c] + EPSV);
      float val = px*wx + py*wy + pz*wz + b1[c];
      val = (val - m1[c])*sc + bt1[c];
      hv[cc] = f2b(fmaxf(val, 0.f));
    }
    *(u16x8*)&A1s[g][swzA1(p, c0)]     = *(u16x8*)&hv[0];
    *(u16x8*)&A1s[g][swzA1(p, c0 + 8)] = *(u16x8*)&hv[8];
  }
  __syncthreads();

  // ---- L2 (128->256): per wave 32 cols x 2 groups; kt-outer
  {
    const int col0 = w*32;
    f32x4 acc[2][2][2];  // [nt][g][m]
    #pragma unroll
    for (int nt = 0; nt < 2; nt++)
      #pragma unroll
      for (int g = 0; g < 2; g++)
        #pragma unroll
        for (int m = 0; m < 2; m++){ f32x4 z = {0.f,0.f,0.f,0.f}; acc[nt][g][m] = z; }
    #pragma unroll
    for (int kt = 0; kt < 4; kt++){
      bf16x8 bA[2][2];
      #pragma unroll
      for (int g = 0; g < 2; g++)
        #pragma unroll
        for (int m = 0; m < 2; m++)
          bA[g][m] = *(const bf16x8*)&A1s[g][swzA1(m*16 + lr, kt*32 + lg*8)];
      bf16x8 bB[2];
      #pragma unroll
      for (int nt = 0; nt < 2; nt++)
        bB[nt] = *(const bf16x8*)(w2b + (size_t)(col0 + nt*16 + lr)*128 + kt*32 + lg*8);
      #pragma unroll
      for (int nt = 0; nt < 2; nt++)
        #pragma unroll
        for (int g = 0; g < 2; g++)
          #pragma unroll
          for (int m = 0; m < 2; m++)
            acc[nt][g][m] = __builtin_amdgcn_mfma_f32_16x16x32_bf16(bA[g][m], bB[nt], acc[nt][g][m], 0,0,0);
    }
    #pragma unroll
    for (int nt = 0; nt < 2; nt++){
      const int col = col0 + nt*16 + lr;
      const float bc = b2[col];
      #pragma unroll
      for (int g = 0; g < 2; g++)
        #pragma unroll
        for (int m = 0; m < 2; m++)
          #pragma unroll
          for (int r = 0; r < 4; r++)
            Fl[g][swzF(m*16 + lg*4 + r, col)] = f2b(acc[nt][g][m][r] + bc);
    }
  }
  __syncthreads();

  // ---- fg = max_k f  (thread: one (g,col))
  {
    const int g = t >> 8, col = t & 255;
    float mx = -__builtin_inff();
    #pragma unroll 4
    for (int row = 0; row < 32; row++) mx = fmaxf(mx, b2f(Fl[g][swzF(row, col)]));
    fgb[g][col] = f2b(mx);
  }
  __syncthreads();

  // ---- L3 (512->512): h = [fg bcast | f]; per wave 64 cols x 2 groups; kt-outer
  {
    const int col0 = w*64;
    f32x4 acc[4][2][2];  // [nt][g][m]
    #pragma unroll
    for (int nt = 0; nt < 4; nt++)
      #pragma unroll
      for (int g = 0; g < 2; g++)
        #pragma unroll
        for (int m = 0; m < 2; m++){ f32x4 z = {0.f,0.f,0.f,0.f}; acc[nt][g][m] = z; }
    #pragma unroll
    for (int kt = 0; kt < 16; kt++){
      bf16x8 bA[2][2];
      if (kt < 8){
        #pragma unroll
        for (int g = 0; g < 2; g++){
          const bf16x8 af = *(const bf16x8*)&fgb[g][kt*32 + lg*8];
          bA[g][0] = af; bA[g][1] = af;
        }
      } else {
        #pragma unroll
        for (int g = 0; g < 2; g++)
          #pragma unroll
          for (int m = 0; m < 2; m++)
            bA[g][m] = *(const bf16x8*)&Fl[g][swzF(m*16 + lr, (kt-8)*32 + lg*8)];
      }
      bf16x8 bB[4];
      #pragma unroll
      for (int nt = 0; nt < 4; nt++)
        bB[nt] = *(const bf16x8*)(w3b + (size_t)(col0 + nt*16 + lr)*512 + kt*32 + lg*8);
      #pragma unroll
      for (int nt = 0; nt < 4; nt++)
        #pragma unroll
        for (int g = 0; g < 2; g++)
          #pragma unroll
          for (int m = 0; m < 2; m++)
            acc[nt][g][m] = __builtin_amdgcn_mfma_f32_16x16x32_bf16(bA[g][m], bB[nt], acc[nt][g][m], 0,0,0);
    }
    #pragma unroll
    for (int nt = 0; nt < 4; nt++){
      const int col = col0 + nt*16 + lr;
      const float bc = b3[col];
      const float sc = g3[col]*rsqrtf(v3[col] + EPSV);
      const float mm = m3[col], bb = bt3[col];
      #pragma unroll
      for (int g = 0; g < 2; g++)
        #pragma unroll
        for (int m = 0; m < 2; m++)
          #pragma unroll
          for (int r = 0; r < 4; r++){
            float val = acc[nt][g][m][r] + bc;
            val = (val - mm)*sc + bb;
            A3s[g][swzA(m*16 + lg*4 + r, col)] = f2b(fmaxf(val, 0.f));
          }
    }
  }
  __syncthreads();

  // ---- L4 (512->384) + maxpool + b4 -> tok; per wave 48 cols x 2 groups; kt-outer
  {
    const int col0 = w*48;
    f32x4 acc[3][2][2];
    #pragma unroll
    for (int nt = 0; nt < 3; nt++)
      #pragma unroll
      for (int g = 0; g < 2; g++)
        #pragma unroll
        for (int m = 0; m < 2; m++){ f32x4 z = {0.f,0.f,0.f,0.f}; acc[nt][g][m] = z; }
    #pragma unroll
    for (int kt = 0; kt < 16; kt++){
      bf16x8 bA[2][2];
      #pragma unroll
      for (int g = 0; g < 2; g++)
        #pragma unroll
        for (int m = 0; m < 2; m++)
          bA[g][m] = *(const bf16x8*)&A3s[g][swzA(m*16 + lr, kt*32 + lg*8)];
      bf16x8 bB[3];
      #pragma unroll
      for (int nt = 0; nt < 3; nt++)
        bB[nt] = *(const bf16x8*)(w4b + (size_t)(col0 + nt*16 + lr)*512 + kt*32 + lg*8);
      #pragma unroll
      for (int nt = 0; nt < 3; nt++)
        #pragma unroll
        for (int g = 0; g < 2; g++)
          #pragma unroll
          for (int m = 0; m < 2; m++)
            acc[nt][g][m] = __builtin_amdgcn_mfma_f32_16x16x32_bf16(bA[g][m], bB[nt], acc[nt][g][m], 0,0,0);
    }
    #pragma unroll
    for (int nt = 0; nt < 3; nt++){
      const int col = col0 + nt*16 + lr;
      const float bc = b4[col];
      #pragma unroll
      for (int g = 0; g < 2; g++){
        float mx = fmaxf(
          fmaxf(fmaxf(acc[nt][g][0][0], acc[nt][g][0][1]), fmaxf(acc[nt][g][0][2], acc[nt][g][0][3])),
          fmaxf(fmaxf(acc[nt][g][1][0], acc[nt][g][1][1]), fmaxf(acc[nt][g][1][2], acc[nt][g][1][3])));
        mx = fmaxf(mx, __shfl_xor(mx, 16));
        mx = fmaxf(mx, __shfl_xor(mx, 32));
        if (lg == 0) tokp[g*C_ + col] = mx + bc;
      }
    }
  }
  __syncthreads();

  // ---- out = tok + pos_embed(center)
  for (int c2 = t; c2 < 2*C_; c2 += 512){
    const int g = (c2 >= C_) ? 1 : 0;
    const int c = c2 - g*C_;
    const int gid = gid0 + g;
    const int d = c >> 7, r = c & 127, m2 = r >> 1;
    const float e = (float)(2*m2) * (1.f/128.f);
    const float dimt = powf(10000.f, e);
    const float ctrd = centers_ord[(size_t)gid*3 + d];
    const float x2 = __fmul_rn(ctrd, 6.28318530717958647692f);
    const float ang = __fdiv_rn(x2, dimt);
    out[(size_t)gid*C_ + c] = tokp[g*C_ + c] + ((r & 1) ? cosf(ang) : sinf(ang));
  }
}

extern "C" void kernel_launch(void* const* d_in, const int* in_sizes, int n_in,
                              void* d_out, int out_size, void* d_ws, size_t ws_size,
                              hipStream_t stream){
  (void)in_sizes; (void)n_in; (void)out_size; (void)ws_size;
  const float* xyz = (const float*)d_in[0];
  const float* w1  = (const float*)d_in[1];
  const float* b1  = (const float*)d_in[2];
  const float* g1  = (const float*)d_in[3];
  const float* bt1 = (const float*)d_in[4];
  const float* m1  = (const float*)d_in[5];
  const float* v1  = (const float*)d_in[6];
  const float* w2  = (const float*)d_in[7];
  const float* b2  = (const float*)d_in[8];
  const float* w3  = (const float*)d_in[9];
  const float* b3  = (const float*)d_in[10];
  const float* g3  = (const float*)d_in[11];
  const float* bt3 = (const float*)d_in[12];
  const float* m3  = (const float*)d_in[13];
  const float* v3  = (const float*)d_in[14];
  const float* w4  = (const float*)d_in[15];
  const float* b4  = (const float*)d_in[16];

  char* ws = (char*)d_ws;
  float* centers_ord  = (float*)(ws + 24576);               // 24576 B
  float* neigh        = (float*)(ws + 49152);               // 786432 B
  unsigned short* w2b = (unsigned short*)(ws + 835584);     // 65536 B
  unsigned short* w3b = (unsigned short*)(ws + 901120);     // 524288 B
  unsigned short* w4b = (unsigned short*)(ws + 1425408);    // 393216 B -> total 1818624 B

  prep_kernel      <<<1920, 256, 0, stream>>>(w2, w3, w4, w2b, w3b, w4b);
  fps_morton_kernel<<<B_, 256, 0, stream>>>(xyz, centers_ord);
  knn_kernel       <<<dim3(G_, B_), 256, 0, stream>>>(xyz, centers_ord, neigh);
  enc_kernel       <<<1024, 512, 0, stream>>>(neigh, centers_ord,
      w1, b1, g1, bt1, m1, v1, w2b, b2, w3b, b3, g3, bt3, m3, v3, w4b, b4,
      (float*)d_out);
}

// Round 10
// 478.361 us; speedup vs baseline: 1.4892x; 1.0686x over previous
//
#include <hip/hip_runtime.h>
#include <hip/hip_bf16.h>

#define B_ 16
#define N_ 8192
#define G_ 128
#define K_ 32
#define C_ 384
#define EPSV 1e-5f

typedef __attribute__((ext_vector_type(8))) short bf16x8;
typedef __attribute__((ext_vector_type(8))) unsigned short u16x8;
typedef __attribute__((ext_vector_type(4))) float f32x4;
typedef __attribute__((ext_vector_type(2))) float f32x2;

__device__ __forceinline__ unsigned short f2b(float f){
  unsigned int u = __float_as_uint(f);
  u += 0x7fffu + ((u >> 16) & 1u);      // RNE (no NaNs in this model)
  return (unsigned short)(u >> 16);
}
__device__ __forceinline__ float b2f(unsigned short s){
  return __uint_as_float(((unsigned int)s) << 16);
}
// exact-order squared distance: ((dx*dx + dy*dy) + dz*dz), IEEE, no contraction
__device__ __forceinline__ float sq3(float dx, float dy, float dz){
  return __fadd_rn(__fadd_rn(__fmul_rn(dx,dx), __fmul_rn(dy,dy)), __fmul_rn(dz,dz));
}
__device__ __forceinline__ f32x2 pkmax(f32x2 a, f32x2 b){
  return f32x2{fmaxf(a.x,b.x), fmaxf(a.y,b.y)};
}
// total-order encode: monotone f32 -> u32 (handles negatives from cancellation)
__device__ __forceinline__ unsigned fenc(float f){
  unsigned u = __float_as_uint(f);
  return ((int)u >= 0) ? (u | 0x80000000u) : ~u;
}

// ---- full-wave DPP reductions (VALU-only; result in lane 63) ----
#define DPP_MAXU_STAGE(r, CTRL) { \
  unsigned _o = (unsigned)__builtin_amdgcn_update_dpp((int)(r), (int)(r), (CTRL), 0xf, 0xf, false); \
  (r) = ((r) > _o) ? (r) : _o; }
#define DPP_MAXU_ALL(r) \
  DPP_MAXU_STAGE(r, 0x111) DPP_MAXU_STAGE(r, 0x112) DPP_MAXU_STAGE(r, 0x114) \
  DPP_MAXU_STAGE(r, 0x118) DPP_MAXU_STAGE(r, 0x142) DPP_MAXU_STAGE(r, 0x143)
#define DPP_MINU_STAGE(r, CTRL) { \
  unsigned _o = (unsigned)__builtin_amdgcn_update_dpp((int)(r), (int)(r), (CTRL), 0xf, 0xf, false); \
  (r) = ((r) < _o) ? (r) : _o; }
#define DPP_MINU_ALL(r) \
  DPP_MINU_STAGE(r, 0x111) DPP_MINU_STAGE(r, 0x112) DPP_MINU_STAGE(r, 0x114) \
  DPP_MINU_STAGE(r, 0x118) DPP_MINU_STAGE(r, 0x142) DPP_MINU_STAGE(r, 0x143)

// ---------------- weight f32->bf16 pre-conversion ----------------
__global__ __launch_bounds__(256) void prep_kernel(
    const float* __restrict__ w2, const float* __restrict__ w3,
    const float* __restrict__ w4, unsigned short* __restrict__ w2b,
    unsigned short* __restrict__ w3b, unsigned short* __restrict__ w4b){
  int i = blockIdx.x*256 + threadIdx.x;
  if (i < 32768){ w2b[i] = f2b(w2[i]); return; }
  i -= 32768;
  if (i < 262144){ w3b[i] = f2b(w3[i]); return; }
  i -= 262144;
  if (i < 196608){ w4b[i] = f2b(w4[i]); }
}

// ---------------- FPS: contiguous ownership + DPP value-tree + ballot ----------------
__attribute__((amdgpu_flat_work_group_size(256,256), amdgpu_waves_per_eu(1,1)))
__global__ void fps_morton_kernel(const float* __restrict__ xyz,
                                  float* __restrict__ centers_ord){
  const int b = blockIdx.x, t = threadIdx.x, w = t >> 6;
  const int lane = t & 63;
  const float* xb = xyz + (size_t)b*N_*3;
  __shared__ __align__(16) float sval[2][4];
  __shared__ __align__(16) int   sidx[2][4];
  __shared__ float clx[G_], cly[G_], clz[G_];
  const int base = t*32;
  f32x2 X[16], Y[16], Z[16], D[16];
  f32x2 mmax;
  const float p0x = xb[0], p0y = xb[1], p0z = xb[2];
  {
#pragma clang fp contract(off)
    float s[96];
    const float4* src = (const float4*)(xb + (size_t)base*3);
    #pragma unroll
    for (int q = 0; q < 24; q++) ((float4*)s)[q] = src[q];
    mmax = f32x2{-1.f, -1.f};
    #pragma unroll
    for (int p = 0; p < 16; p++){
      X[p] = f32x2{s[6*p+0], s[6*p+3]};
      Y[p] = f32x2{s[6*p+1], s[6*p+4]};
      Z[p] = f32x2{s[6*p+2], s[6*p+5]};
      const f32x2 dx = X[p] - p0x, dy = Y[p] - p0y, dz = Z[p] - p0z;
      D[p] = (dx*dx + dy*dy) + dz*dz;
      mmax = pkmax(mmax, D[p]);
    }
  }
  if (t == 0){ clx[0] = p0x; cly[0] = p0y; clz[0] = p0z; }
  int buf = 0;
  for (int g = 1; g < G_; g++){
    const float v = fmaxf(mmax.x, mmax.y);
    int jl = 0;
    #pragma unroll
    for (int p = 15; p >= 0; p--){
      if (D[p].y == v) jl = 2*p+1;
      if (D[p].x == v) jl = 2*p;
    }
    const unsigned uv = __float_as_uint(v);
    unsigned r = uv;
    DPP_MAXU_ALL(r)
    const unsigned wmax = (unsigned)__builtin_amdgcn_readlane((int)r, 63);
    const unsigned long long tie = __ballot(uv == wmax);
    const int wl = __ffsll(tie) - 1;
    if (lane == wl){ sval[buf][w] = __uint_as_float(wmax); sidx[buf][w] = base + jl; }
    __syncthreads();
    const float4 vv = *(const float4*)&sval[buf][0];
    const int4   ii = *(const int4*)&sidx[buf][0];
    float bv = vv.x; int bb = ii.x;
    if (vv.y > bv){ bv = vv.y; bb = ii.y; }
    if (vv.z > bv){ bv = vv.z; bb = ii.z; }
    if (vv.w > bv){ bv = vv.w; bb = ii.w; }
    {
#pragma clang fp contract(off)
      const int ubb = __builtin_amdgcn_readfirstlane(bb);
      const float cx = xb[ubb*3], cy = xb[ubb*3+1], cz = xb[ubb*3+2];
      if (t == 0){ clx[g] = cx; cly[g] = cy; clz[g] = cz; }
      mmax = f32x2{-1.f, -1.f};
      #pragma unroll
      for (int p = 0; p < 16; p++){
        const f32x2 dx = X[p] - cx, dy = Y[p] - cy, dz = Z[p] - cz;
        const f32x2 dn = (dx*dx + dy*dy) + dz*dz;
        D[p] = f32x2{fminf(D[p].x, dn.x), fminf(D[p].y, dn.y)};
        mmax = pkmax(mmax, D[p]);
      }
    }
    buf ^= 1;
  }
  __syncthreads();
  if (t < 64){
    float mcx[2], mcy[2], mcz[2]; bool mvis[2];
    #pragma unroll
    for (int j = 0; j < 2; j++){
      const int idx = lane + j*64;
      mcx[j] = clx[idx]; mcy[j] = cly[idx]; mcz[j] = clz[idx];
      mvis[j] = (idx == 0);
    }
    float curx = clx[0], cury = cly[0], curz = clz[0];
    if (lane == 0){
      centers_ord[(size_t)b*G_*3 + 0] = curx;
      centers_ord[(size_t)b*G_*3 + 1] = cury;
      centers_ord[(size_t)b*G_*3 + 2] = curz;
    }
    for (int step = 1; step < G_; step++){
      const float d0r = sq3(__fsub_rn(mcx[0],curx), __fsub_rn(mcy[0],cury), __fsub_rn(mcz[0],curz));
      const float d1r = sq3(__fsub_rn(mcx[1],curx), __fsub_rn(mcy[1],cury), __fsub_rn(mcz[1],curz));
      const float d0 = mvis[0] ? __builtin_inff() : d0r;
      const float d1 = mvis[1] ? __builtin_inff() : d1r;
      float mv = d0; int mi = lane;
      if (d1 < mv){ mv = d1; mi = lane + 64; }
      const int wj = mi >> 6;
      const float sx = wj ? mcx[1] : mcx[0];
      const float sy = wj ? mcy[1] : mcy[0];
      const float sz = wj ? mcz[1] : mcz[0];
      const unsigned key = __float_as_uint(mv);
      unsigned r = key;
      DPP_MINU_ALL(r)
      const unsigned wmin = (unsigned)__builtin_amdgcn_readlane((int)r, 63);
      const unsigned long long tie = __ballot(key == wmin);
      int wl;
      if (__popcll(tie) == 1){
        wl = __ffsll(tie) - 1;
      } else {
        float tv = mv; int ti = mi;
        #pragma unroll
        for (int mk = 1; mk < 64; mk <<= 1){
          const float ov = __shfl_xor(tv, mk);
          const int   oi = __shfl_xor(ti, mk);
          if (ov < tv || (ov == tv && oi < ti)){ tv = ov; ti = oi; }
        }
        wl = ti & 63;
      }
      const int mbi = __builtin_amdgcn_readlane(mi, wl);
      curx = __uint_as_float((unsigned)__builtin_amdgcn_readlane((int)__float_as_uint(sx), wl));
      cury = __uint_as_float((unsigned)__builtin_amdgcn_readlane((int)__float_as_uint(sy), wl));
      curz = __uint_as_float((unsigned)__builtin_amdgcn_readlane((int)__float_as_uint(sz), wl));
      if (lane == wl){
        if ((mbi >> 6) == 0) mvis[0] = true; else mvis[1] = true;
      }
      if (lane == 0){
        centers_ord[((size_t)b*G_ + step)*3 + 0] = curx;
        centers_ord[((size_t)b*G_ + step)*3 + 1] = cury;
        centers_ord[((size_t)b*G_ + step)*3 + 2] = curz;
      }
    }
  }
}

// ---------------- KNN: contiguous ownership + DPP min tree + ballot ----------------
__global__ __launch_bounds__(256, 2) void knn_kernel(const float* __restrict__ xyz,
                                                     const float* __restrict__ centers_ord,
                                                     float* __restrict__ neigh){
  const int gp = blockIdx.x, b = blockIdx.y, t = threadIdx.x;
  const int lane = t & 63, w = t >> 6;
  __shared__ __align__(16) float sv[2][4];
  __shared__ __align__(16) int   si[2][4];
  __shared__ int list[K_];
  const float* xb = xyz + (size_t)b*N_*3;
  const float* cp = centers_ord + ((size_t)b*G_ + gp)*3;
  const float cxv = cp[0], cyv = cp[1], czv = cp[2];
  const float cc = sq3(cxv, cyv, czv);
  const int base = t*32;
  float dd[32];
  float v = __builtin_inff(); int jl = 0;
  {
    float s[96];
    const float4* src = (const float4*)(xb + (size_t)base*3);
    #pragma unroll
    for (int q = 0; q < 24; q++) ((float4*)s)[q] = src[q];
    #pragma unroll
    for (int j = 0; j < 32; j++){
      const float x = s[3*j], y = s[3*j+1], z = s[3*j+2];
      const float xx = sq3(x, y, z);
      const float dot = __fadd_rn(__fadd_rn(__fmul_rn(cxv,x), __fmul_rn(cyv,y)), __fmul_rn(czv,z));
      dd[j] = __fsub_rn(__fadd_rn(cc, xx), __fmul_rn(2.f, dot));
      if (dd[j] < v){ v = dd[j]; jl = j; }
    }
  }
  int buf = 0;
  for (int it = 0; it < K_; it++){
    const unsigned key = fenc(v);
    unsigned r = key;
    DPP_MINU_ALL(r)
    const unsigned wmin = (unsigned)__builtin_amdgcn_readlane((int)r, 63);
    const unsigned long long tie = __ballot(key == wmin);
    const int wl = __ffsll(tie) - 1;
    if (lane == wl){ sv[buf][w] = v; si[buf][w] = base + jl; }
    __syncthreads();
    const float4 vv = *(const float4*)&sv[buf][0];
    const int4   ii = *(const int4*)&si[buf][0];
    float bv = vv.x; int bb = ii.x;
    if (vv.y < bv){ bv = vv.y; bb = ii.y; }
    if (vv.z < bv){ bv = vv.z; bb = ii.z; }
    if (vv.w < bv){ bv = vv.w; bb = ii.w; }
    if (t == 0) list[it] = bb;
    if ((bb >> 5) == t){
      const int jw = bb & 31;
      #pragma unroll
      for (int j = 0; j < 32; j++) if (j == jw) dd[j] = __builtin_inff();
      v = __builtin_inff(); jl = 0;
      #pragma unroll
      for (int j = 0; j < 32; j++) if (dd[j] < v){ v = dd[j]; jl = j; }
    }
    buf ^= 1;
  }
  __syncthreads();
  if (t < K_*3){
    const int k = t / 3, d = t % 3;
    const int n = list[k];
    neigh[(((size_t)b*G_ + gp)*K_ + k)*3 + d] = __fsub_rn(xb[n*3+d], cp[d]);
  }
}

// ---------------- encoder: 3 groups/block via LDS lifetime overlays ----------------
__device__ __forceinline__ int swzA1(int row, int col){  // [32][128] bf16
  int byteo = row*256 + col*2;
  byteo ^= (row & 7) << 4;
  return byteo >> 1;
}
__device__ __forceinline__ int swzF(int row, int col){  // [32][256] bf16
  int byteo = row*512 + col*2;
  byteo ^= (row & 7) << 4;
  return byteo >> 1;
}
__device__ __forceinline__ int swzA(int row, int col){  // [32][512] bf16
  int byteo = row*1024 + col*2;
  byteo ^= (row & 7) << 4;
  return byteo >> 1;
}

#define NG3 3

__global__ __launch_bounds__(512, 2) void enc_kernel(
    const float* __restrict__ neigh, const float* __restrict__ centers_ord,
    const float* __restrict__ w1, const float* __restrict__ b1,
    const float* __restrict__ g1, const float* __restrict__ bt1,
    const float* __restrict__ m1, const float* __restrict__ v1,
    const unsigned short* __restrict__ w2b, const float* __restrict__ b2,
    const unsigned short* __restrict__ w3b, const float* __restrict__ b3,
    const float* __restrict__ g3, const float* __restrict__ bt3,
    const float* __restrict__ m3, const float* __restrict__ v3,
    const unsigned short* __restrict__ w4b, const float* __restrict__ b4,
    float* __restrict__ out)
{
  const int t = threadIdx.x;
  const int lane = t & 63, w = t >> 6, lr = lane & 15, lg = lane >> 4;
  const int gid0 = blockIdx.x*NG3;
  const int ng = min(NG3, 2048 - gid0);   // tail block: 2 groups
  // LDS overlays (lifetimes):  A1s [L1,L2) overlays A3s [L3,L4);  tok [L4,..) overlays Fl [L2,L3)
  __shared__ __align__(16) char smem[148992];
  unsigned short* A3s = (unsigned short*)smem;              // [3][32*512]
  unsigned short* A1s = (unsigned short*)smem;              // [3][32*128] (overlay)
  unsigned short* Flp = (unsigned short*)(smem + 98304);    // [3][32*256]
  unsigned short* fgb = (unsigned short*)(smem + 147456);   // [3][256]
  float* tokp = (float*)(smem + 98304);                     // [3][384] (overlay of Fl)

  // ---- L1 (3->128) + BN + ReLU -> A1s   (768 items: (g, point, channel-octet-pair))
  for (int it = t; it < NG3*256; it += 512){
    const int g = it >> 8, rem = it & 255, p = rem >> 3, c0 = (rem & 7) * 16;
    const float* pgp = neigh + (size_t)(gid0 + g)*96 + p*3;   // tail g: in-ws garbage, masked at out
    const float px = pgp[0], py = pgp[1], pz = pgp[2];
    unsigned short hv[16];
    #pragma unroll
    for (int cc = 0; cc < 16; cc++){
      const int c = c0 + cc;
      const float wx = w1[c*3], wy = w1[c*3+1], wz = w1[c*3+2];
      const float sc = g1[c] * rsqrtf(v1[c] + EPSV);
      float val = px*wx + py*wy + pz*wz + b1[c];
      val = (val - m1[c])*sc + bt1[c];
      hv[cc] = f2b(fmaxf(val, 0.f));
    }
    *(u16x8*)&A1s[g*4096 + swzA1(p, c0)]     = *(u16x8*)&hv[0];
    *(u16x8*)&A1s[g*4096 + swzA1(p, c0 + 8)] = *(u16x8*)&hv[8];
  }
  __syncthreads();

  // ---- L2 (128->256): per wave 32 cols x 3 groups; kt-outer
  {
    const int col0 = w*32;
    f32x4 acc[2][NG3][2];  // [nt][g][m]
    #pragma unroll
    for (int nt = 0; nt < 2; nt++)
      #pragma unroll
      for (int g = 0; g < NG3; g++)
        #pragma unroll
        for (int m = 0; m < 2; m++){ f32x4 z = {0.f,0.f,0.f,0.f}; acc[nt][g][m] = z; }
    #pragma unroll
    for (int kt = 0; kt < 4; kt++){
      bf16x8 bA[NG3][2];
      #pragma unroll
      for (int g = 0; g < NG3; g++)
        #pragma unroll
        for (int m = 0; m < 2; m++)
          bA[g][m] = *(const bf16x8*)&A1s[g*4096 + swzA1(m*16 + lr, kt*32 + lg*8)];
      bf16x8 bB[2];
      #pragma unroll
      for (int nt = 0; nt < 2; nt++)
        bB[nt] = *(const bf16x8*)(w2b + (size_t)(col0 + nt*16 + lr)*128 + kt*32 + lg*8);
      #pragma unroll
      for (int nt = 0; nt < 2; nt++)
        #pragma unroll
        for (int g = 0; g < NG3; g++)
          #pragma unroll
          for (int m = 0; m < 2; m++)
            acc[nt][g][m] = __builtin_amdgcn_mfma_f32_16x16x32_bf16(bA[g][m], bB[nt], acc[nt][g][m], 0,0,0);
    }
    #pragma unroll
    for (int nt = 0; nt < 2; nt++){
      const int col = col0 + nt*16 + lr;
      const float bc = b2[col];
      #pragma unroll
      for (int g = 0; g < NG3; g++)
        #pragma unroll
        for (int m = 0; m < 2; m++)
          #pragma unroll
          for (int r = 0; r < 4; r++)
            Flp[g*8192 + swzF(m*16 + lg*4 + r, col)] = f2b(acc[nt][g][m][r] + bc);
    }
  }
  __syncthreads();

  // ---- fg = max_k f
  for (int it = t; it < NG3*256; it += 512){
    const int g = it >> 8, col = it & 255;
    float mx = -__builtin_inff();
    #pragma unroll 4
    for (int row = 0; row < 32; row++) mx = fmaxf(mx, b2f(Flp[g*8192 + swzF(row, col)]));
    fgb[g*256 + col] = f2b(mx);
  }
  __syncthreads();

  // ---- L3 (512->512): h = [fg bcast | f]; per wave 64 cols x 3 groups; kt-outer
  {
    const int col0 = w*64;
    f32x4 acc[4][NG3][2];
    #pragma unroll
    for (int nt = 0; nt < 4; nt++)
      #pragma unroll
      for (int g = 0; g < NG3; g++)
        #pragma unroll
        for (int m = 0; m < 2; m++){ f32x4 z = {0.f,0.f,0.f,0.f}; acc[nt][g][m] = z; }
    #pragma unroll
    for (int kt = 0; kt < 16; kt++){
      bf16x8 bA[NG3][2];
      if (kt < 8){
        #pragma unroll
        for (int g = 0; g < NG3; g++){
          const bf16x8 af = *(const bf16x8*)&fgb[g*256 + kt*32 + lg*8];
          bA[g][0] = af; bA[g][1] = af;
        }
      } else {
        #pragma unroll
        for (int g = 0; g < NG3; g++)
          #pragma unroll
          for (int m = 0; m < 2; m++)
            bA[g][m] = *(const bf16x8*)&Flp[g*8192 + swzF(m*16 + lr, (kt-8)*32 + lg*8)];
      }
      bf16x8 bB[4];
      #pragma unroll
      for (int nt = 0; nt < 4; nt++)
        bB[nt] = *(const bf16x8*)(w3b + (size_t)(col0 + nt*16 + lr)*512 + kt*32 + lg*8);
      #pragma unroll
      for (int nt = 0; nt < 4; nt++)
        #pragma unroll
        for (int g = 0; g < NG3; g++)
          #pragma unroll
          for (int m = 0; m < 2; m++)
            acc[nt][g][m] = __builtin_amdgcn_mfma_f32_16x16x32_bf16(bA[g][m], bB[nt], acc[nt][g][m], 0,0,0);
    }
    #pragma unroll
    for (int nt = 0; nt < 4; nt++){
      const int col = col0 + nt*16 + lr;
      const float bc = b3[col];
      const float sc = g3[col]*rsqrtf(v3[col] + EPSV);
      const float mm = m3[col], bb = bt3[col];
      #pragma unroll
      for (int g = 0; g < NG3; g++)
        #pragma unroll
        for (int m = 0; m < 2; m++)
          #pragma unroll
          for (int r = 0; r < 4; r++){
            float val = acc[nt][g][m][r] + bc;
            val = (val - mm)*sc + bb;
            A3s[g*16384 + swzA(m*16 + lg*4 + r, col)] = f2b(fmaxf(val, 0.f));
          }
    }
  }
  __syncthreads();

  // ---- L4 (512->384) + maxpool + b4 -> tok; per wave 48 cols x 3 groups; kt-outer
  {
    const int col0 = w*48;
    f32x4 acc[3][NG3][2];
    #pragma unroll
    for (int nt = 0; nt < 3; nt++)
      #pragma unroll
      for (int g = 0; g < NG3; g++)
        #pragma unroll
        for (int m = 0; m < 2; m++){ f32x4 z = {0.f,0.f,0.f,0.f}; acc[nt][g][m] = z; }
    #pragma unroll
    for (int kt = 0; kt < 16; kt++){
      bf16x8 bA[NG3][2];
      #pragma unroll
      for (int g = 0; g < NG3; g++)
        #pragma unroll
        for (int m = 0; m < 2; m++)
          bA[g][m] = *(const bf16x8*)&A3s[g*16384 + swzA(m*16 + lr, kt*32 + lg*8)];
      bf16x8 bB[3];
      #pragma unroll
      for (int nt = 0; nt < 3; nt++)
        bB[nt] = *(const bf16x8*)(w4b + (size_t)(col0 + nt*16 + lr)*512 + kt*32 + lg*8);
      #pragma unroll
      for (int nt = 0; nt < 3; nt++)
        #pragma unroll
        for (int g = 0; g < NG3; g++)
          #pragma unroll
          for (int m = 0; m < 2; m++)
            acc[nt][g][m] = __builtin_amdgcn_mfma_f32_16x16x32_bf16(bA[g][m], bB[nt], acc[nt][g][m], 0,0,0);
    }
    #pragma unroll
    for (int nt = 0; nt < 3; nt++){
      const int col = col0 + nt*16 + lr;
      const float bc = b4[col];
      #pragma unroll
      for (int g = 0; g < NG3; g++){
        float mx = fmaxf(
          fmaxf(fmaxf(acc[nt][g][0][0], acc[nt][g][0][1]), fmaxf(acc[nt][g][0][2], acc[nt][g][0][3])),
          fmaxf(fmaxf(acc[nt][g][1][0], acc[nt][g][1][1]), fmaxf(acc[nt][g][1][2], acc[nt][g][1][3])));
        mx = fmaxf(mx, __shfl_xor(mx, 16));
        mx = fmaxf(mx, __shfl_xor(mx, 32));
        if (lg == 0) tokp[g*C_ + col] = mx + bc;
      }
    }
  }
  __syncthreads();

  // ---- out = tok + pos_embed(center)   (write-guarded for the tail block)
  #pragma unroll
  for (int g = 0; g < NG3; g++){
    if (g >= ng) break;
    const int gid = gid0 + g;
    for (int c = t; c < C_; c += 512){
      const int d = c >> 7, r = c & 127, m2 = r >> 1;
      const float e = (float)(2*m2) * (1.f/128.f);
      const float dimt = powf(10000.f, e);
      const float ctrd = centers_ord[(size_t)gid*3 + d];
      const float x2 = __fmul_rn(ctrd, 6.28318530717958647692f);
      const float ang = __fdiv_rn(x2, dimt);
      out[(size_t)gid*C_ + c] = tokp[g*C_ + c] + ((r & 1) ? cosf(ang) : sinf(ang));
    }
  }
}

extern "C" void kernel_launch(void* const* d_in, const int* in_sizes, int n_in,
                              void* d_out, int out_size, void* d_ws, size_t ws_size,
                              hipStream_t stream){
  (void)in_sizes; (void)n_in; (void)out_size; (void)ws_size;
  const float* xyz = (const float*)d_in[0];
  const float* w1  = (const float*)d_in[1];
  const float* b1  = (const float*)d_in[2];
  const float* g1  = (const float*)d_in[3];
  const float* bt1 = (const float*)d_in[4];
  const float* m1  = (const float*)d_in[5];
  const float* v1  = (const float*)d_in[6];
  const float* w2  = (const float*)d_in[7];
  const float* b2  = (const float*)d_in[8];
  const float* w3  = (const float*)d_in[9];
  const float* b3  = (const float*)d_in[10];
  const float* g3  = (const float*)d_in[11];
  const float* bt3 = (const float*)d_in[12];
  const float* m3  = (const float*)d_in[13];
  const float* v3  = (const float*)d_in[14];
  const float* w4  = (const float*)d_in[15];
  const float* b4  = (const float*)d_in[16];

  char* ws = (char*)d_ws;
  float* centers_ord  = (float*)(ws + 24576);               // 24576 B
  float* neigh        = (float*)(ws + 49152);               // 786432 B
  unsigned short* w2b = (unsigned short*)(ws + 835584);     // 65536 B
  unsigned short* w3b = (unsigned short*)(ws + 901120);     // 524288 B
  unsigned short* w4b = (unsigned short*)(ws + 1425408);    // 393216 B -> total 1818624 B

  prep_kernel      <<<1920, 256, 0, stream>>>(w2, w3, w4, w2b, w3b, w4b);
  fps_morton_kernel<<<B_, 256, 0, stream>>>(xyz, centers_ord);
  knn_kernel       <<<dim3(G_, B_), 256, 0, stream>>>(xyz, centers_ord, neigh);
  enc_kernel       <<<683, 512, 0, stream>>>(neigh, centers_ord,
      w1, b1, g1, bt1, m1, v1, w2b, b2, w3b, b3, g3, bt3, m3, v3, w4b, b4,
      (float*)d_out);
}